// Round 8
// baseline (183.637 us; speedup 1.0000x reference)
//
#include <hip/hip_runtime.h>

#define B_ 4
#define N_ 4096
#define ROWS (B_ * N_)            // 16384 rows per side
#define PTS_TOTAL (2 * ROWS)      // 32768 points total

#define LOG2E 1.4426950408889634f
#define LN2   0.6931471805599453f
#define EPS1  1e-4f               /* BLUR^P */
#define NEG_LOG2M (-12.0f)        /* -log2(4096) */
#define ENC_STRIDE 32

typedef float f2 __attribute__((ext_vector_type(2)));

__device__ inline unsigned fenc(float f) {
  unsigned u = __float_as_uint(f);
  return (u & 0x80000000u) ? ~u : (u | 0x80000000u);
}
__device__ inline float fdec(unsigned u) {
  return (u & 0x80000000u) ? __uint_as_float(u & 0x7fffffffu)
                           : __uint_as_float(~u);
}
__device__ inline float fexp2(float x) { return __builtin_amdgcn_exp2f(x); }
__device__ inline float flog2(float x) { return __builtin_amdgcn_logf(x); }

__global__ void init_kernel(unsigned* enc) {
  if (threadIdx.x < 13) enc[threadIdx.x * ENC_STRIDE] = 0u;
}

// ---- reduce: max coord-norm^2, per-dim max & min (flip-encoded) ----
__global__ __launch_bounds__(256) void reduce_kernel(
    const float* __restrict__ x, const float* __restrict__ y,
    unsigned* __restrict__ enc) {
  int idx = blockIdx.x * 256 + threadIdx.x;   // 0..32767
  bool isx = idx < ROWS;
  const float* p = (isx ? x : y) + (size_t)(isx ? idx : idx - ROWS) * 6;
  float d[6];
#pragma unroll
  for (int k = 0; k < 6; ++k) d[k] = p[k];
  unsigned e[13];
  e[0] = fenc(d[0] * d[0] + d[1] * d[1] + d[2] * d[2]);
#pragma unroll
  for (int k = 0; k < 6; ++k) {
    e[1 + k] = fenc(d[k]);
    e[7 + k] = fenc(-d[k]);
  }
#pragma unroll
  for (int off = 32; off > 0; off >>= 1) {
#pragma unroll
    for (int k = 0; k < 13; ++k) {
      unsigned o = (unsigned)__shfl_xor((int)e[k], off);
      e[k] = e[k] > o ? e[k] : o;
    }
  }
  __shared__ unsigned sh[4][13];
  int wave = threadIdx.x >> 6, lane = threadIdx.x & 63;
  if (lane == 0) {
#pragma unroll
    for (int k = 0; k < 13; ++k) sh[wave][k] = e[k];
  }
  __syncthreads();
  if (threadIdx.x < 13) {
    unsigned v = sh[0][threadIdx.x];
#pragma unroll
    for (int w = 1; w < 4; ++w) v = v > sh[w][threadIdx.x] ? v : sh[w][threadIdx.x];
    atomicMax(&enc[threadIdx.x * ENC_STRIDE], v);
  }
}

// ---- pack: AoS rows (8f); columns pair-interleaved (2 cols / 12f); hh0 ----
__global__ __launch_bounds__(256) void pack_kernel(
    const float* __restrict__ x, const float* __restrict__ y,
    float4* __restrict__ XP, float4* __restrict__ YP,
    float* __restrict__ CX, float* __restrict__ CY,
    float* __restrict__ HHX0, float* __restrict__ HHY0,
    const unsigned* __restrict__ enc, float* __restrict__ sc) {
  int idx = blockIdx.x * 256 + threadIdx.x;  // 0..32767
  float maxnorm = sqrtf(fdec(enc[0]));
  float s = 1.0f / (maxnorm + 1e-6f);
  float eps0 = 0.0f;
#pragma unroll
  for (int k = 0; k < 6; ++k) {
    float mx = fdec(enc[(1 + k) * ENC_STRIDE]);
    float mn = -fdec(enc[(7 + k) * ENC_STRIDE]);
    float dd = mx - mn;
    eps0 += dd * dd;
  }
  if (idx == 0) sc[0] = eps0;

  bool isx = idx < ROWS;
  int local = isx ? idx : idx - ROWS;
  const float* p = (isx ? x : y) + (size_t)local * 6;
  float v[6];
  v[0] = p[0] * s; v[1] = p[1] * s; v[2] = p[2] * s;
  v[3] = 0.1f * fminf(fmaxf(p[3], 0.0f), 1.0f);
  v[4] = 0.1f * fminf(fmaxf(p[4], 0.0f), 1.0f);
  v[5] = 0.1f * fminf(fmaxf(p[5], 0.0f), 1.0f);
  float q = v[0]*v[0] + v[1]*v[1] + v[2]*v[2] + v[3]*v[3] + v[4]*v[4] + v[5]*v[5];
  float4* P = isx ? XP : YP;
  P[(size_t)local * 2]     = make_float4(v[0], v[1], v[2], v[3]);
  P[(size_t)local * 2 + 1] = make_float4(v[4], v[5], q, 0.0f);
  float* C = (isx ? CX : CY) + (size_t)(local >> 1) * 12 + (local & 1);
#pragma unroll
  for (int d = 0; d < 6; ++d) C[d * 2] = v[d];
  float hh0 = NEG_LOG2M - q * (LOG2E / eps0);
  (isx ? HHX0 : HHY0)[local] = hh0;
}

// ==== eps0 softmin via 2nd-order Taylor moments ============================
__global__ __launch_bounds__(256) void mom_kernel(
    const float* __restrict__ CX, const float* __restrict__ CY,
    const float* __restrict__ hhX, const float* __restrict__ hhY,
    float* __restrict__ MOMX, float* __restrict__ MOMY) {
  int side = blockIdx.x >> 2, batch = blockIdx.x & 3;
  const float* C = side ? CY : CX;
  const float* hh = side ? hhY : hhX;
  float* M = (side ? MOMY : MOMX) + batch * 32;
  float acc[28];
#pragma unroll
  for (int k = 0; k < 28; ++k) acc[k] = 0.0f;
  for (int k = 0; k < 16; ++k) {
    int j = batch * 4096 + k * 256 + threadIdx.x;
    float w = fexp2(hh[j]);
    const float* cp = C + (size_t)(j >> 1) * 12 + (j & 1);
    float c[6];
#pragma unroll
    for (int d = 0; d < 6; ++d) c[d] = cp[2 * d];
    acc[0] += w;
    int kk = 1;
#pragma unroll
    for (int d = 0; d < 6; ++d) acc[kk++] += w * c[d];
#pragma unroll
    for (int d = 0; d < 6; ++d) {
      float wc = w * c[d];
#pragma unroll
      for (int e = d; e < 6; ++e) acc[kk++] += wc * c[e];
    }
  }
  int wave = threadIdx.x >> 6, lane = threadIdx.x & 63;
#pragma unroll
  for (int off = 32; off > 0; off >>= 1) {
#pragma unroll
    for (int k = 0; k < 28; ++k) acc[k] += __shfl_xor(acc[k], off);
  }
  __shared__ float sh[4][28];
  if (lane == 0) {
#pragma unroll
    for (int k = 0; k < 28; ++k) sh[wave][k] = acc[k];
  }
  __syncthreads();
  if (threadIdx.x < 28)
    M[threadIdx.x] = (sh[0][threadIdx.x] + sh[1][threadIdx.x]) +
                     (sh[2][threadIdx.x] + sh[3][threadIdx.x]);
}

// rows: f = q - eps*ln2*log2(W + ln2*(p.M1) + ln2^2/2 * p^T M2 p)
__global__ __launch_bounds__(256) void rows_kernel(
    const float4* __restrict__ XP, const float4* __restrict__ YP,
    const float* __restrict__ MOMX, const float* __restrict__ MOMY,
    const float* __restrict__ prevF, const float* __restrict__ prevG,
    float* __restrict__ outF, float* __restrict__ outG,
    float* __restrict__ hhFo, float* __restrict__ hhGo,
    const float* __restrict__ sc, int next_sel) {
  int g = blockIdx.x * 256 + threadIdx.x;     // 0..32767
  int side = g >> 14, lrow = g & (ROWS - 1), b = lrow >> 12;
  const float4* rows = side ? YP : XP;
  const float* M = (side ? MOMX : MOMY) + b * 32;   // opposite-side moments
  const float* prev = side ? prevG : prevF;
  float* out = side ? outG : outF;
  float* hho = side ? hhGo : hhFo;
  float eps = sc[0];
  float sc2 = 2.0f * LOG2E / eps;
  float4 a = rows[(size_t)lrow * 2];
  float4 bb = rows[(size_t)lrow * 2 + 1];
  float p[6] = {a.x * sc2, a.y * sc2, a.z * sc2,
                a.w * sc2, bb.x * sc2, bb.y * sc2};
  float q = bb.z;
  float W = M[0];
  float t1 = 0.0f;
#pragma unroll
  for (int d = 0; d < 6; ++d) t1 += p[d] * M[1 + d];
  float t2 = 0.0f;
  int kk = 7;
#pragma unroll
  for (int d = 0; d < 6; ++d) {
#pragma unroll
    for (int e = d; e < 6; ++e) {
      float coef = (d == e) ? 1.0f : 2.0f;
      t2 += coef * p[d] * p[e] * M[kk];
      kk++;
    }
  }
  float S = W + LN2 * t1 + (0.5f * LN2 * LN2) * t2;
  float f_t = q - eps * LN2 * flog2(S);
  float fo = prev ? 0.5f * (prev[lrow] + f_t) : f_t;
  out[lrow] = fo;
  float inv_next = next_sel ? (1.0f / sc[0]) : (1.0f / EPS1);
  hho[lrow] = NEG_LOG2M + (fo - q) * (inv_next * LOG2E);
}

// ==== eps1 softmin (pairs 3,4): pure max; 8 rows/wave, 2048-col halves =====
// 2048 blocks x 4 waves: block = 2 rowgroups x 2 column halves.
__global__ __launch_bounds__(256) void softmax_pair_kernel(
    const float4* __restrict__ XP, const float4* __restrict__ YP,
    const float* __restrict__ CX, const float* __restrict__ CY,
    const float* __restrict__ hhY, const float* __restrict__ hhX,
    const float* __restrict__ prevF, const float* __restrict__ prevG,
    float* __restrict__ outF, float* __restrict__ outG,
    float* __restrict__ hhFo, float* __restrict__ hhGo) {
  int wave = threadIdx.x >> 6, lane = threadIdx.x & 63;
  int rgl = wave >> 1, half = wave & 1;
  int rg = blockIdx.x * 2 + rgl;              // 0..4095
  int grow0 = rg * 8;
  int dir = grow0 >> 14;
  int lrow0 = grow0 & (ROWS - 1);
  const float4* rows = dir ? YP : XP;
  const float* cols  = dir ? CX : CY;
  const float* hh    = dir ? hhX : hhY;
  const float* prev  = dir ? prevG : prevF;
  float* out = dir ? outG : outF;
  float* hho = dir ? hhGo : hhFo;

  const float eps = EPS1;
  const float sc2 = 2.0f * LOG2E / EPS1;

  float P[8][6];
#pragma unroll
  for (int r = 0; r < 8; ++r) {
    float4 a = rows[(size_t)(lrow0 + r) * 2];
    float4 b = rows[(size_t)(lrow0 + r) * 2 + 1];
    P[r][0] = a.x * sc2; P[r][1] = a.y * sc2; P[r][2] = a.z * sc2;
    P[r][3] = a.w * sc2; P[r][4] = b.x * sc2; P[r][5] = b.y * sc2;
  }

  int cb = (lrow0 >> 12) << 12;
  int rec0 = (cb >> 1) + half * 1024 + lane;  // pair-record index
  const float4* cpt = (const float4*)(cols + (size_t)rec0 * 12);
  const float2* hpt = (const float2*)(hh + cb) + half * 1024 + lane;

  f2 m2[8];
#pragma unroll
  for (int r = 0; r < 8; ++r) m2[r] = f2{-3.0e38f, -3.0e38f};

#pragma unroll 2
  for (int t = 0; t < 16; ++t) {
    float4 c0 = cpt[0], c1 = cpt[1], c2 = cpt[2];
    float2 h2 = hpt[0];
    cpt += 192;  hpt += 64;
    f2 H = f2{h2.x, h2.y};
    f2 D0 = f2{c0.x, c0.y}, D1 = f2{c0.z, c0.w};
    f2 D2 = f2{c1.x, c1.y}, D3 = f2{c1.z, c1.w};
    f2 D4 = f2{c2.x, c2.y}, D5 = f2{c2.z, c2.w};
#pragma unroll
    for (int r = 0; r < 8; ++r) {
      f2 v = H;
      v = __builtin_elementwise_fma(D0, f2{P[r][0], P[r][0]}, v);
      v = __builtin_elementwise_fma(D1, f2{P[r][1], P[r][1]}, v);
      v = __builtin_elementwise_fma(D2, f2{P[r][2], P[r][2]}, v);
      v = __builtin_elementwise_fma(D3, f2{P[r][3], P[r][3]}, v);
      v = __builtin_elementwise_fma(D4, f2{P[r][4], P[r][4]}, v);
      v = __builtin_elementwise_fma(D5, f2{P[r][5], P[r][5]}, v);
      m2[r] = __builtin_elementwise_max(m2[r], v);
    }
  }

  float m[8];
#pragma unroll
  for (int r = 0; r < 8; ++r) m[r] = fmaxf(m2[r].x, m2[r].y);
#pragma unroll
  for (int off = 32; off > 0; off >>= 1) {
#pragma unroll
    for (int r = 0; r < 8; ++r) m[r] = fmaxf(m[r], __shfl_xor(m[r], off));
  }

  __shared__ float msh[2][8];
  if (half == 1 && lane == 0) {
#pragma unroll
    for (int r = 0; r < 8; ++r) msh[rgl][r] = m[r];
  }
  __syncthreads();
  if (half == 0 && lane == 0) {
    const float inv_next = 1.0f / EPS1;
#pragma unroll
    for (int r = 0; r < 8; ++r) {
      float mm = fmaxf(m[r], msh[rgl][r]);
      int row = lrow0 + r;
      float q = rows[(size_t)row * 2 + 1].z;
      float f_t = q - eps * LN2 * mm;     // logsumexp == max at eps=1e-4
      float fo = prev ? 0.5f * (prev[row] + f_t) : f_t;
      out[row] = fo;
      if (hho) hho[row] = NEG_LOG2M + (fo - q) * (inv_next * LOG2E);
    }
  }
}

// ---- final: 10/(B*N) * (sum f_new + sum g_new) ----
__global__ __launch_bounds__(256) void final_kernel(
    const float* __restrict__ FN, const float* __restrict__ GN,
    float* __restrict__ out) {
  float acc = 0.0f;
  for (int i = threadIdx.x; i < ROWS; i += 256) acc += FN[i] + GN[i];
  __shared__ float sh[256];
  sh[threadIdx.x] = acc;
  __syncthreads();
  for (int st = 128; st > 0; st >>= 1) {
    if (threadIdx.x < st) sh[threadIdx.x] += sh[threadIdx.x + st];
    __syncthreads();
  }
  if (threadIdx.x == 0) out[0] = sh[0] * (10.0f / (float)(B_ * N_));
}

extern "C" void kernel_launch(void* const* d_in, const int* in_sizes, int n_in,
                              void* d_out, int out_size, void* d_ws,
                              size_t ws_size, hipStream_t stream) {
  const float* x = (const float*)d_in[0];
  const float* y = (const float*)d_in[1];
  float* out = (float*)d_out;
  float* w = (float*)d_ws;
  unsigned* enc = (unsigned*)d_ws;        // 13 slots at stride 32
  float* sc = w + 448;                    // sc[0] = eps0

  float* base = w + 512;
  float4* XP = (float4*)base;                       // 131072 floats
  float4* YP = (float4*)(base + 131072);            // 131072
  float* CX = base + 262144;                        // 98304 (8192 rec * 12)
  float* CY = base + 360448;                        // 98304
  float* HHX0 = base + 458752;                      // 16384
  float* HHY0 = base + 475136;                      // 16384
  float* F1 = base + 491520;
  float* G1 = F1 + ROWS;
  float* F2 = G1 + ROWS;
  float* G2 = F2 + ROWS;
  float* HF1 = G2 + ROWS;
  float* HG1 = HF1 + ROWS;
  float* HF2 = HG1 + ROWS;
  float* HG2 = HF2 + ROWS;
  float* MOMX = HG2 + ROWS;                         // 4*32
  float* MOMY = MOMX + 128;                         // 4*32
  // lifetime-safe aliases
  float* F3 = F1;
  float* G3 = G1;
  float* FN = F2;
  float* GN = G2;
  float* HF3 = HHX0;
  float* HG3 = HHY0;

  init_kernel<<<1, 64, 0, stream>>>(enc);
  reduce_kernel<<<PTS_TOTAL / 256, 256, 0, stream>>>(x, y, enc);
  pack_kernel<<<PTS_TOTAL / 256, 256, 0, stream>>>(x, y, XP, YP, CX, CY,
                                                   HHX0, HHY0, enc, sc);
  // pair 1 (eps0, analytic): f1,g1 + HF1,HG1 (next eps0)
  mom_kernel<<<8, 256, 0, stream>>>(CX, CY, HHX0, HHY0, MOMX, MOMY);
  rows_kernel<<<PTS_TOTAL / 256, 256, 0, stream>>>(XP, YP, MOMX, MOMY, nullptr,
                                                   nullptr, F1, G1, HF1, HG1,
                                                   sc, 1);
  // pair 2 (eps0, analytic): f2,g2 + HF2,HG2 (next eps1)
  mom_kernel<<<8, 256, 0, stream>>>(CX, CY, HF1, HG1, MOMX, MOMY);
  rows_kernel<<<PTS_TOTAL / 256, 256, 0, stream>>>(XP, YP, MOMX, MOMY, F1, G1,
                                                   F2, G2, HF2, HG2, sc, 0);
  // pair 3 (eps1, max): f3 = .5(f2+SM_xy(HG2)); g3 = .5(g2+SM_yx(HF2))
  softmax_pair_kernel<<<2048, 256, 0, stream>>>(XP, YP, CX, CY, HG2, HF2, F2,
                                                G2, F3, G3, HF3, HG3);
  // pair 4 (eps1, max): f_new = SM_xy(HG3); g_new = SM_yx(HF3)
  softmax_pair_kernel<<<2048, 256, 0, stream>>>(XP, YP, CX, CY, HG3, HF3,
                                                nullptr, nullptr, FN, GN,
                                                nullptr, nullptr);
  final_kernel<<<1, 256, 0, stream>>>(FN, GN, out);
}

// Round 9
// 171.120 us; speedup vs baseline: 1.0732x; 1.0732x over previous
//
#include <hip/hip_runtime.h>

#define B_ 4
#define N_ 4096
#define ROWS (B_ * N_)            // 16384 rows per side
#define PTS_TOTAL (2 * ROWS)      // 32768 points total

#define LOG2E 1.4426950408889634f
#define LN2   0.6931471805599453f
#define EPS1  1e-4f               /* BLUR^P */
#define NEG_LOG2M (-12.0f)        /* -log2(4096) */
#define ENC_STRIDE 32

typedef float f2 __attribute__((ext_vector_type(2)));

__device__ inline unsigned fenc(float f) {
  unsigned u = __float_as_uint(f);
  return (u & 0x80000000u) ? ~u : (u | 0x80000000u);
}
__device__ inline float fdec(unsigned u) {
  return (u & 0x80000000u) ? __uint_as_float(u & 0x7fffffffu)
                           : __uint_as_float(~u);
}
__device__ inline float fexp2(float x) { return __builtin_amdgcn_exp2f(x); }
__device__ inline float flog2(float x) { return __builtin_amdgcn_logf(x); }

__global__ void init_kernel(unsigned* enc) {
  if (threadIdx.x < 13) enc[threadIdx.x * ENC_STRIDE] = 0u;
}

// ---- reduce: max coord-norm^2, per-dim max & min (flip-encoded) ----
__global__ __launch_bounds__(256) void reduce_kernel(
    const float* __restrict__ x, const float* __restrict__ y,
    unsigned* __restrict__ enc) {
  int idx = blockIdx.x * 256 + threadIdx.x;   // 0..32767
  bool isx = idx < ROWS;
  const float* p = (isx ? x : y) + (size_t)(isx ? idx : idx - ROWS) * 6;
  float d[6];
#pragma unroll
  for (int k = 0; k < 6; ++k) d[k] = p[k];
  unsigned e[13];
  e[0] = fenc(d[0] * d[0] + d[1] * d[1] + d[2] * d[2]);
#pragma unroll
  for (int k = 0; k < 6; ++k) {
    e[1 + k] = fenc(d[k]);
    e[7 + k] = fenc(-d[k]);
  }
#pragma unroll
  for (int off = 32; off > 0; off >>= 1) {
#pragma unroll
    for (int k = 0; k < 13; ++k) {
      unsigned o = (unsigned)__shfl_xor((int)e[k], off);
      e[k] = e[k] > o ? e[k] : o;
    }
  }
  __shared__ unsigned sh[4][13];
  int wave = threadIdx.x >> 6, lane = threadIdx.x & 63;
  if (lane == 0) {
#pragma unroll
    for (int k = 0; k < 13; ++k) sh[wave][k] = e[k];
  }
  __syncthreads();
  if (threadIdx.x < 13) {
    unsigned v = sh[0][threadIdx.x];
#pragma unroll
    for (int w = 1; w < 4; ++w) v = v > sh[w][threadIdx.x] ? v : sh[w][threadIdx.x];
    atomicMax(&enc[threadIdx.x * ENC_STRIDE], v);
  }
}

// ---- pack: AoS rows (8f); columns pair-interleaved (2 cols / 12f); hh0 ----
__global__ __launch_bounds__(256) void pack_kernel(
    const float* __restrict__ x, const float* __restrict__ y,
    float4* __restrict__ XP, float4* __restrict__ YP,
    float* __restrict__ CX, float* __restrict__ CY,
    float* __restrict__ HHX0, float* __restrict__ HHY0,
    const unsigned* __restrict__ enc, float* __restrict__ sc) {
  int idx = blockIdx.x * 256 + threadIdx.x;  // 0..32767
  float maxnorm = sqrtf(fdec(enc[0]));
  float s = 1.0f / (maxnorm + 1e-6f);
  float eps0 = 0.0f;
#pragma unroll
  for (int k = 0; k < 6; ++k) {
    float mx = fdec(enc[(1 + k) * ENC_STRIDE]);
    float mn = -fdec(enc[(7 + k) * ENC_STRIDE]);
    float dd = mx - mn;
    eps0 += dd * dd;
  }
  if (idx == 0) sc[0] = eps0;

  bool isx = idx < ROWS;
  int local = isx ? idx : idx - ROWS;
  const float* p = (isx ? x : y) + (size_t)local * 6;
  float v[6];
  v[0] = p[0] * s; v[1] = p[1] * s; v[2] = p[2] * s;
  v[3] = 0.1f * fminf(fmaxf(p[3], 0.0f), 1.0f);
  v[4] = 0.1f * fminf(fmaxf(p[4], 0.0f), 1.0f);
  v[5] = 0.1f * fminf(fmaxf(p[5], 0.0f), 1.0f);
  float q = v[0]*v[0] + v[1]*v[1] + v[2]*v[2] + v[3]*v[3] + v[4]*v[4] + v[5]*v[5];
  float4* P = isx ? XP : YP;
  P[(size_t)local * 2]     = make_float4(v[0], v[1], v[2], v[3]);
  P[(size_t)local * 2 + 1] = make_float4(v[4], v[5], q, 0.0f);
  float* C = (isx ? CX : CY) + (size_t)(local >> 1) * 12 + (local & 1);
#pragma unroll
  for (int d = 0; d < 6; ++d) C[d * 2] = v[d];
  float hh0 = NEG_LOG2M - q * (LOG2E / eps0);
  (isx ? HHX0 : HHY0)[local] = hh0;
}

// ==== eps0 softmin via 2nd-order Taylor moments (vectorized loads) =========
__global__ __launch_bounds__(256) void mom_kernel(
    const float* __restrict__ CX, const float* __restrict__ CY,
    const float* __restrict__ hhX, const float* __restrict__ hhY,
    float* __restrict__ MOMX, float* __restrict__ MOMY) {
  int side = blockIdx.x >> 2, batch = blockIdx.x & 3;
  const float* C = side ? CY : CX;
  const float* hh = side ? hhY : hhX;
  float* M = (side ? MOMY : MOMX) + batch * 32;
  const float4* cr = (const float4*)(C + (size_t)batch * 2048 * 12);
  const float2* hr = (const float2*)(hh + batch * 4096);
  float acc[28];
#pragma unroll
  for (int k = 0; k < 28; ++k) acc[k] = 0.0f;
#pragma unroll 2
  for (int it = 0; it < 8; ++it) {
    int rec = it * 256 + threadIdx.x;
    float4 c0 = cr[(size_t)rec * 3];
    float4 c1 = cr[(size_t)rec * 3 + 1];
    float4 c2 = cr[(size_t)rec * 3 + 2];
    float2 h2 = hr[rec];
    float wA = fexp2(h2.x), wB = fexp2(h2.y);
    float cA[6] = {c0.x, c0.z, c1.x, c1.z, c2.x, c2.z};
    float cB[6] = {c0.y, c0.w, c1.y, c1.w, c2.y, c2.w};
    acc[0] += wA + wB;
    int kk = 1;
#pragma unroll
    for (int d = 0; d < 6; ++d) acc[kk++] += wA * cA[d] + wB * cB[d];
#pragma unroll
    for (int d = 0; d < 6; ++d) {
      float wa = wA * cA[d], wb = wB * cB[d];
#pragma unroll
      for (int e = d; e < 6; ++e) acc[kk++] += wa * cA[e] + wb * cB[e];
    }
  }
  int wave = threadIdx.x >> 6, lane = threadIdx.x & 63;
#pragma unroll
  for (int off = 32; off > 0; off >>= 1) {
#pragma unroll
    for (int k = 0; k < 28; ++k) acc[k] += __shfl_xor(acc[k], off);
  }
  __shared__ float sh[4][28];
  if (lane == 0) {
#pragma unroll
    for (int k = 0; k < 28; ++k) sh[wave][k] = acc[k];
  }
  __syncthreads();
  if (threadIdx.x < 28)
    M[threadIdx.x] = (sh[0][threadIdx.x] + sh[1][threadIdx.x]) +
                     (sh[2][threadIdx.x] + sh[3][threadIdx.x]);
}

// rows: f = q - eps*ln2*log2(W + ln2*(p.M1) + ln2^2/2 * p^T M2 p)
__global__ __launch_bounds__(256) void rows_kernel(
    const float4* __restrict__ XP, const float4* __restrict__ YP,
    const float* __restrict__ MOMX, const float* __restrict__ MOMY,
    const float* __restrict__ prevF, const float* __restrict__ prevG,
    float* __restrict__ outF, float* __restrict__ outG,
    float* __restrict__ hhFo, float* __restrict__ hhGo,
    const float* __restrict__ sc, int next_sel) {
  int g = blockIdx.x * 256 + threadIdx.x;     // 0..32767
  int side = g >> 14, lrow = g & (ROWS - 1), b = lrow >> 12;
  const float4* rows = side ? YP : XP;
  const float* M = (side ? MOMX : MOMY) + b * 32;   // opposite-side moments
  const float* prev = side ? prevG : prevF;
  float* out = side ? outG : outF;
  float* hho = side ? hhGo : hhFo;
  float eps = sc[0];
  float sc2 = 2.0f * LOG2E / eps;
  float4 a = rows[(size_t)lrow * 2];
  float4 bb = rows[(size_t)lrow * 2 + 1];
  float p[6] = {a.x * sc2, a.y * sc2, a.z * sc2,
                a.w * sc2, bb.x * sc2, bb.y * sc2};
  float q = bb.z;
  float W = M[0];
  float t1 = 0.0f;
#pragma unroll
  for (int d = 0; d < 6; ++d) t1 += p[d] * M[1 + d];
  float t2 = 0.0f;
  int kk = 7;
#pragma unroll
  for (int d = 0; d < 6; ++d) {
#pragma unroll
    for (int e = d; e < 6; ++e) {
      float coef = (d == e) ? 1.0f : 2.0f;
      t2 += coef * p[d] * p[e] * M[kk];
      kk++;
    }
  }
  float S = W + LN2 * t1 + (0.5f * LN2 * LN2) * t2;
  float f_t = q - eps * LN2 * flog2(S);
  float fo = prev ? 0.5f * (prev[lrow] + f_t) : f_t;
  out[lrow] = fo;
  float inv_next = next_sel ? (1.0f / sc[0]) : (1.0f / EPS1);
  hho[lrow] = NEG_LOG2M + (fo - q) * (inv_next * LOG2E);
}

// ==== eps1 softmin (pairs 3,4): pure max; LDS-staged columns ===============
// block = 32 rows (4 waves x 8), sweeps 4096 cols in 32 stripes of 128 cols.
// Stripe staged to LDS as 7 f2-arrays (reads 2-way bank-aliased = free).
__global__ __launch_bounds__(256) void softmax_pair_kernel(
    const float4* __restrict__ XP, const float4* __restrict__ YP,
    const float* __restrict__ CX, const float* __restrict__ CY,
    const float* __restrict__ hhY, const float* __restrict__ hhX,
    const float* __restrict__ prevF, const float* __restrict__ prevG,
    float* __restrict__ outF, float* __restrict__ outG,
    float* __restrict__ hhFo, float* __restrict__ hhGo) {
  int t = threadIdx.x;
  int wave = t >> 6, lane = t & 63;
  int grow0 = blockIdx.x * 32 + wave * 8;     // this wave's first global row
  int dir = grow0 >> 14;                      // 0: xy, 1: yx
  int lrow0 = grow0 & (ROWS - 1);
  const float4* rows = dir ? YP : XP;
  const float* cols  = dir ? CX : CY;
  const float* hh    = dir ? hhX : hhY;
  const float* prev  = dir ? prevG : prevF;
  float* out = dir ? outG : outF;
  float* hho = dir ? hhGo : hhFo;

  const float eps = EPS1;
  const float sc2 = 2.0f * LOG2E / EPS1;

  float P[8][6];
#pragma unroll
  for (int r = 0; r < 8; ++r) {
    float4 a = rows[(size_t)(lrow0 + r) * 2];
    float4 b = rows[(size_t)(lrow0 + r) * 2 + 1];
    P[r][0] = a.x * sc2; P[r][1] = a.y * sc2; P[r][2] = a.z * sc2;
    P[r][3] = a.w * sc2; P[r][4] = b.x * sc2; P[r][5] = b.y * sc2;
  }

  int cb = (lrow0 >> 12) << 12;               // batch column base (uniform)
  // stripe s: dims float4 idx s*192 + t (t<192); hh float4 idx s*32 + (t-192)
  const float4* dimp = (const float4*)(cols) + (size_t)(cb >> 1) * 3;
  const float4* hhp  = (const float4*)(hh + cb);

  __shared__ f2 sh[2][7][64];                 // 7168 B

  // staging decode for this thread
  int drec = 0, dk = 0, hj = 0;
  bool isdim = t < 192, ishh = (t >= 192) && (t < 224);
  if (isdim) { drec = t / 3; dk = t % 3; }
  if (ishh)  { hj = t - 192; }

  float4 rv = make_float4(0.f, 0.f, 0.f, 0.f);
  if (isdim) rv = dimp[t];
  else if (ishh) rv = hhp[hj];

  f2 m2[8];
#pragma unroll
  for (int r = 0; r < 8; ++r) m2[r] = f2{-3.0e38f, -3.0e38f};

  for (int s = 0; s < 32; ++s) {
    int b = s & 1;
    __syncthreads();                          // all done reading buf b (s-2)
    if (isdim) {
      sh[b][2 * dk][drec]     = f2{rv.x, rv.y};
      sh[b][2 * dk + 1][drec] = f2{rv.z, rv.w};
    } else if (ishh) {
      sh[b][6][2 * hj]     = f2{rv.x, rv.y};
      sh[b][6][2 * hj + 1] = f2{rv.z, rv.w};
    }
    __syncthreads();                          // buf b ready
    if (s + 1 < 32) {
      if (isdim) rv = dimp[(s + 1) * 192 + t];
      else if (ishh) rv = hhp[(s + 1) * 32 + hj];
    }
    f2 D0 = sh[b][0][lane], D1 = sh[b][1][lane], D2 = sh[b][2][lane];
    f2 D3 = sh[b][3][lane], D4 = sh[b][4][lane], D5 = sh[b][5][lane];
    f2 H  = sh[b][6][lane];
#pragma unroll
    for (int r = 0; r < 8; ++r) {
      f2 v = H;
      v = __builtin_elementwise_fma(D0, f2{P[r][0], P[r][0]}, v);
      v = __builtin_elementwise_fma(D1, f2{P[r][1], P[r][1]}, v);
      v = __builtin_elementwise_fma(D2, f2{P[r][2], P[r][2]}, v);
      v = __builtin_elementwise_fma(D3, f2{P[r][3], P[r][3]}, v);
      v = __builtin_elementwise_fma(D4, f2{P[r][4], P[r][4]}, v);
      v = __builtin_elementwise_fma(D5, f2{P[r][5], P[r][5]}, v);
      m2[r] = __builtin_elementwise_max(m2[r], v);
    }
  }

  float m[8];
#pragma unroll
  for (int r = 0; r < 8; ++r) m[r] = fmaxf(m2[r].x, m2[r].y);
#pragma unroll
  for (int off = 32; off > 0; off >>= 1) {
#pragma unroll
    for (int r = 0; r < 8; ++r) m[r] = fmaxf(m[r], __shfl_xor(m[r], off));
  }
  if (lane == 0) {
    const float inv_next = 1.0f / EPS1;
#pragma unroll
    for (int r = 0; r < 8; ++r) {
      int row = lrow0 + r;
      float q = rows[(size_t)row * 2 + 1].z;
      float f_t = q - eps * LN2 * m[r];       // logsumexp == max at eps=1e-4
      float fo = prev ? 0.5f * (prev[row] + f_t) : f_t;
      out[row] = fo;
      if (hho) hho[row] = NEG_LOG2M + (fo - q) * (inv_next * LOG2E);
    }
  }
}

// ---- final: 10/(B*N) * (sum f_new + sum g_new) ----
__global__ __launch_bounds__(256) void final_kernel(
    const float* __restrict__ FN, const float* __restrict__ GN,
    float* __restrict__ out) {
  float acc = 0.0f;
  for (int i = threadIdx.x; i < ROWS; i += 256) acc += FN[i] + GN[i];
  __shared__ float sh[256];
  sh[threadIdx.x] = acc;
  __syncthreads();
  for (int st = 128; st > 0; st >>= 1) {
    if (threadIdx.x < st) sh[threadIdx.x] += sh[threadIdx.x + st];
    __syncthreads();
  }
  if (threadIdx.x == 0) out[0] = sh[0] * (10.0f / (float)(B_ * N_));
}

extern "C" void kernel_launch(void* const* d_in, const int* in_sizes, int n_in,
                              void* d_out, int out_size, void* d_ws,
                              size_t ws_size, hipStream_t stream) {
  const float* x = (const float*)d_in[0];
  const float* y = (const float*)d_in[1];
  float* out = (float*)d_out;
  float* w = (float*)d_ws;
  unsigned* enc = (unsigned*)d_ws;        // 13 slots at stride 32
  float* sc = w + 448;                    // sc[0] = eps0

  float* base = w + 512;
  float4* XP = (float4*)base;                       // 131072 floats
  float4* YP = (float4*)(base + 131072);            // 131072
  float* CX = base + 262144;                        // 98304 (8192 rec * 12)
  float* CY = base + 360448;                        // 98304
  float* HHX0 = base + 458752;                      // 16384
  float* HHY0 = base + 475136;                      // 16384
  float* F1 = base + 491520;
  float* G1 = F1 + ROWS;
  float* F2 = G1 + ROWS;
  float* G2 = F2 + ROWS;
  float* HF1 = G2 + ROWS;
  float* HG1 = HF1 + ROWS;
  float* HF2 = HG1 + ROWS;
  float* HG2 = HF2 + ROWS;
  float* MOMX = HG2 + ROWS;                         // 4*32
  float* MOMY = MOMX + 128;                         // 4*32
  // lifetime-safe aliases
  float* F3 = F1;
  float* G3 = G1;
  float* FN = F2;
  float* GN = G2;
  float* HF3 = HHX0;
  float* HG3 = HHY0;

  init_kernel<<<1, 64, 0, stream>>>(enc);
  reduce_kernel<<<PTS_TOTAL / 256, 256, 0, stream>>>(x, y, enc);
  pack_kernel<<<PTS_TOTAL / 256, 256, 0, stream>>>(x, y, XP, YP, CX, CY,
                                                   HHX0, HHY0, enc, sc);
  // pair 1 (eps0, analytic): f1,g1 + HF1,HG1 (next eps0)
  mom_kernel<<<8, 256, 0, stream>>>(CX, CY, HHX0, HHY0, MOMX, MOMY);
  rows_kernel<<<PTS_TOTAL / 256, 256, 0, stream>>>(XP, YP, MOMX, MOMY, nullptr,
                                                   nullptr, F1, G1, HF1, HG1,
                                                   sc, 1);
  // pair 2 (eps0, analytic): f2,g2 + HF2,HG2 (next eps1)
  mom_kernel<<<8, 256, 0, stream>>>(CX, CY, HF1, HG1, MOMX, MOMY);
  rows_kernel<<<PTS_TOTAL / 256, 256, 0, stream>>>(XP, YP, MOMX, MOMY, F1, G1,
                                                   F2, G2, HF2, HG2, sc, 0);
  // pair 3 (eps1, max): f3 = .5(f2+SM_xy(HG2)); g3 = .5(g2+SM_yx(HF2))
  softmax_pair_kernel<<<1024, 256, 0, stream>>>(XP, YP, CX, CY, HG2, HF2, F2,
                                                G2, F3, G3, HF3, HG3);
  // pair 4 (eps1, max): f_new = SM_xy(HG3); g_new = SM_yx(HF3)
  softmax_pair_kernel<<<1024, 256, 0, stream>>>(XP, YP, CX, CY, HG3, HF3,
                                                nullptr, nullptr, FN, GN,
                                                nullptr, nullptr);
  final_kernel<<<1, 256, 0, stream>>>(FN, GN, out);
}

// Round 10
// 168.249 us; speedup vs baseline: 1.0915x; 1.0171x over previous
//
#include <hip/hip_runtime.h>

#define B_ 4
#define N_ 4096
#define ROWS (B_ * N_)            // 16384 per side
#define PTS_TOTAL (2 * ROWS)      // 32768 points

#define LOG2E 1.4426950408889634f
#define LN2   0.6931471805599453f
#define EPS1  1e-4f
#define NEG_LOG2M (-12.0f)              /* -log2(4096) */
#define EPS1LNM 8.317766166719343e-4f   /* eps1 * ln(4096) */

typedef _Float16 h2 __attribute__((ext_vector_type(2)));

__device__ inline float fexp2(float x) { return __builtin_amdgcn_exp2f(x); }
__device__ inline float flog2(float x) { return __builtin_amdgcn_logf(x); }

__device__ inline float fdot2f(h2 a, h2 b, float c) {
#if defined(__has_builtin) && __has_builtin(__builtin_amdgcn_fdot2)
  return __builtin_amdgcn_fdot2(a, b, c, false);
#else
  return (float)a.x * (float)b.x + (float)a.y * (float)b.y + c;
#endif
}
__device__ inline h2 bch2(unsigned u) { return __builtin_bit_cast(h2, u); }
__device__ inline unsigned pkh2(float a, float b) {
  h2 hv; hv.x = (_Float16)a; hv.y = (_Float16)b;
  return __builtin_bit_cast(unsigned, hv);
}

// ==== K1: single-block setup: 13 global maxes -> eps0, s; zero MOM =========
__global__ __launch_bounds__(1024) void setup_kernel(
    const float* __restrict__ x, const float* __restrict__ y,
    float* __restrict__ sc, float* __restrict__ MOM) {
  int t = threadIdx.x;
  if (t < 512) MOM[t] = 0.0f;               // zero both moment banks
  float mx[13];
#pragma unroll
  for (int k = 0; k < 13; ++k) mx[k] = -3.0e38f;
  for (int k = 0; k < 32; ++k) {
    int idx = k * 1024 + t;                 // 0..32767
    bool isx = idx < ROWS;
    const float2* p2 =
        (const float2*)((isx ? x : y) + (size_t)(isx ? idx : idx - ROWS) * 6);
    float2 a = p2[0], b = p2[1], c = p2[2];
    float d[6] = {a.x, a.y, b.x, b.y, c.x, c.y};
    mx[0] = fmaxf(mx[0], d[0]*d[0] + d[1]*d[1] + d[2]*d[2]);
#pragma unroll
    for (int j = 0; j < 6; ++j) {
      mx[1 + j] = fmaxf(mx[1 + j], d[j]);
      mx[7 + j] = fmaxf(mx[7 + j], -d[j]);
    }
  }
#pragma unroll
  for (int off = 32; off > 0; off >>= 1) {
#pragma unroll
    for (int k = 0; k < 13; ++k) mx[k] = fmaxf(mx[k], __shfl_xor(mx[k], off));
  }
  __shared__ float sh[16][13];
  int wave = t >> 6, lane = t & 63;
  if (lane == 0) {
#pragma unroll
    for (int k = 0; k < 13; ++k) sh[wave][k] = mx[k];
  }
  __syncthreads();
  if (t < 13) {
    float v = sh[0][t];
#pragma unroll
    for (int w = 1; w < 16; ++w) v = fmaxf(v, sh[w][t]);
    sh[0][t] = v;
  }
  __syncthreads();
  if (t == 0) {
    float s = 1.0f / (sqrtf(sh[0][0]) + 1e-6f);
    float eps0 = 0.0f;
#pragma unroll
    for (int k = 0; k < 6; ++k) {
      float dd = sh[0][1 + k] + sh[0][7 + k];   // max - min
      eps0 += dd * dd;
    }
    sc[0] = eps0;
    sc[1] = s;
  }
}

// ==== K2: pack XP (f32) + 16B f16 records + mom1 partials ==================
__global__ __launch_bounds__(256) void pack_kernel(
    const float* __restrict__ x, const float* __restrict__ y,
    float4* __restrict__ XP, uint4* __restrict__ CREC,
    const float* __restrict__ sc, float* __restrict__ MOM1) {
  int g = blockIdx.x * 256 + threadIdx.x;   // 0..32767
  int side = g >> 14, local = g & (ROWS - 1), batch = local >> 12;
  float eps0 = sc[0], s = sc[1];
  const float* p = (side ? y : x) + (size_t)local * 6;
  float v[6];
  v[0] = p[0] * s; v[1] = p[1] * s; v[2] = p[2] * s;
  v[3] = 0.1f * fminf(fmaxf(p[3], 0.0f), 1.0f);
  v[4] = 0.1f * fminf(fmaxf(p[4], 0.0f), 1.0f);
  v[5] = 0.1f * fminf(fmaxf(p[5], 0.0f), 1.0f);
  float q = v[0]*v[0] + v[1]*v[1] + v[2]*v[2] + v[3]*v[3] + v[4]*v[4] + v[5]*v[5];
  XP[(size_t)g * 2]     = make_float4(v[0], v[1], v[2], v[3]);
  XP[(size_t)g * 2 + 1] = make_float4(v[4], v[5], q, 0.0f);
  CREC[g] = (uint4){pkh2(v[0], v[1]), pkh2(v[2], v[3]), pkh2(v[4], v[5]), 0u};

  // mom1 partials: w0 = 2^(-log2M - q*log2e/eps0)
  float w = fexp2(NEG_LOG2M - q * (LOG2E / eps0));
  float acc[28];
  acc[0] = w;
  int kk = 1;
#pragma unroll
  for (int d = 0; d < 6; ++d) acc[kk++] = w * v[d];
#pragma unroll
  for (int d = 0; d < 6; ++d) {
    float wv = w * v[d];
#pragma unroll
    for (int e = d; e < 6; ++e) acc[kk++] = wv * v[e];
  }
#pragma unroll
  for (int off = 32; off > 0; off >>= 1) {
#pragma unroll
    for (int k = 0; k < 28; ++k) acc[k] += __shfl_xor(acc[k], off);
  }
  __shared__ float sh[4][28];
  int wave = threadIdx.x >> 6, lane = threadIdx.x & 63;
  if (lane == 0) {
#pragma unroll
    for (int k = 0; k < 28; ++k) sh[wave][k] = acc[k];
  }
  __syncthreads();
  if (threadIdx.x < 28) {
    float vv = (sh[0][threadIdx.x] + sh[1][threadIdx.x]) +
               (sh[2][threadIdx.x] + sh[3][threadIdx.x]);
    atomicAdd(&MOM1[(side * 4 + batch) * 32 + threadIdx.x], vv);
  }
}

// ---- Taylor softmin evaluation helper (eps0 regime) ----
__device__ inline float taylor_f(const float* __restrict__ M, const float* v,
                                 float q, float eps0) {
  float sc2 = 2.0f * LOG2E / eps0;
  float p[6];
#pragma unroll
  for (int d = 0; d < 6; ++d) p[d] = v[d] * sc2;
  float t1 = 0.0f;
#pragma unroll
  for (int d = 0; d < 6; ++d) t1 += p[d] * M[1 + d];
  float t2 = 0.0f;
  int kk = 7;
#pragma unroll
  for (int d = 0; d < 6; ++d) {
#pragma unroll
    for (int e = d; e < 6; ++e) {
      float coef = (d == e) ? 1.0f : 2.0f;
      t2 += coef * p[d] * p[e] * M[kk];
      kk++;
    }
  }
  float S = M[0] + LN2 * t1 + (0.5f * LN2 * LN2) * t2;
  return q - eps0 * LN2 * flog2(S);
}

// ==== K3: rows pair-1 + mom2 partials ======================================
__global__ __launch_bounds__(256) void rows1_kernel(
    const float4* __restrict__ XP, const float* __restrict__ MOM1,
    float* __restrict__ MOM2, float* __restrict__ FG1,
    const float* __restrict__ sc) {
  int g = blockIdx.x * 256 + threadIdx.x;
  int side = g >> 14, local = g & (ROWS - 1), batch = local >> 12;
  float eps0 = sc[0];
  float4 a = XP[(size_t)g * 2], b = XP[(size_t)g * 2 + 1];
  float v[6] = {a.x, a.y, a.z, a.w, b.x, b.y};
  float q = b.z;
  const float* M = MOM1 + (((side ^ 1) * 4 + batch) * 32);
  float f1 = taylor_f(M, v, q, eps0);
  FG1[g] = f1;
  // mom2 partials with w = 2^(-log2M + (f1-q)*log2e/eps0)
  float w = fexp2(NEG_LOG2M + (f1 - q) * (LOG2E / eps0));
  float acc[28];
  acc[0] = w;
  int kk = 1;
#pragma unroll
  for (int d = 0; d < 6; ++d) acc[kk++] = w * v[d];
#pragma unroll
  for (int d = 0; d < 6; ++d) {
    float wv = w * v[d];
#pragma unroll
    for (int e = d; e < 6; ++e) acc[kk++] = wv * v[e];
  }
#pragma unroll
  for (int off = 32; off > 0; off >>= 1) {
#pragma unroll
    for (int k = 0; k < 28; ++k) acc[k] += __shfl_xor(acc[k], off);
  }
  __shared__ float sh[4][28];
  int wave = threadIdx.x >> 6, lane = threadIdx.x & 63;
  if (lane == 0) {
#pragma unroll
    for (int k = 0; k < 28; ++k) sh[wave][k] = acc[k];
  }
  __syncthreads();
  if (threadIdx.x < 28) {
    float vv = (sh[0][threadIdx.x] + sh[1][threadIdx.x]) +
               (sh[2][threadIdx.x] + sh[3][threadIdx.x]);
    atomicAdd(&MOM2[(side * 4 + batch) * 32 + threadIdx.x], vv);
  }
}

// ==== K4: rows pair-2 -> FG2 + rescaled half-units Hs2 =====================
__global__ __launch_bounds__(256) void rows2_kernel(
    const float4* __restrict__ XP, const float* __restrict__ MOM2,
    const float* __restrict__ FG1, float* __restrict__ FG2,
    float* __restrict__ Hs2, const float* __restrict__ sc) {
  int g = blockIdx.x * 256 + threadIdx.x;
  int side = g >> 14, local = g & (ROWS - 1), batch = local >> 12;
  float eps0 = sc[0];
  float4 a = XP[(size_t)g * 2], b = XP[(size_t)g * 2 + 1];
  float v[6] = {a.x, a.y, a.z, a.w, b.x, b.y};
  float q = b.z;
  const float* M = MOM2 + (((side ^ 1) * 4 + batch) * 32);
  float f_t = taylor_f(M, v, q, eps0);
  float f2 = 0.5f * (FG1[g] + f_t);
  FG2[g] = f2;
  Hs2[g] = 0.5f * (f2 - q - EPS1LNM);   // half-units for the f16 max kernels
}

// ==== K5/K6: eps1 softmin (pure max) with fdot2 f16 ========================
// block = 32 rows (2 rowgroups x 16), each rowgroup split over 2 col halves.
__global__ __launch_bounds__(256) void softmax_pair_kernel(
    const uint4* __restrict__ CREC, const float* __restrict__ XPf,
    const float* __restrict__ Hs_in, const float* __restrict__ prev,
    float* __restrict__ outp, float* __restrict__ Hs_out) {
  int t = threadIdx.x;
  int wave = t >> 6, lane = t & 63;
  int rgl = wave >> 1, half = wave & 1;
  int grow0 = blockIdx.x * 32 + rgl * 16;     // global row base (0..32767)
  int side = grow0 >> 14;
  int batch = (grow0 & (ROWS - 1)) >> 12;
  int colrec0 = (side ^ 1) * ROWS + batch * 4096 + half * 2048;

  h2 P01[16], P23[16], P45[16];
#pragma unroll
  for (int r = 0; r < 16; ++r) {
    uint4 R = CREC[grow0 + r];
    P01[r] = bch2(R.x); P23[r] = bch2(R.y); P45[r] = bch2(R.z);
  }

  float m[16];
#pragma unroll
  for (int r = 0; r < 16; ++r) m[r] = -3.0e38f;

#pragma unroll 2
  for (int it = 0; it < 16; ++it) {
    int j0 = colrec0 + it * 128 + 2 * lane;
    uint4 A = CREC[j0];
    uint4 Bv = CREC[j0 + 1];
    float2 hs = *(const float2*)(Hs_in + j0);
    h2 a01 = bch2(A.x), a23 = bch2(A.y), a45 = bch2(A.z);
    h2 b01 = bch2(Bv.x), b23 = bch2(Bv.y), b45 = bch2(Bv.z);
#pragma unroll
    for (int r = 0; r < 16; ++r) {
      float v1 = fdot2f(a01, P01[r], hs.x);
      v1 = fdot2f(a23, P23[r], v1);
      v1 = fdot2f(a45, P45[r], v1);
      float v2 = fdot2f(b01, P01[r], hs.y);
      v2 = fdot2f(b23, P23[r], v2);
      v2 = fdot2f(b45, P45[r], v2);
      m[r] = fmaxf(m[r], fmaxf(v1, v2));
    }
  }

#pragma unroll
  for (int off = 32; off > 0; off >>= 1) {
#pragma unroll
    for (int r = 0; r < 16; ++r) m[r] = fmaxf(m[r], __shfl_xor(m[r], off));
  }

  __shared__ float msh[2][16];
  if (half == 1 && lane == 0) {
#pragma unroll
    for (int r = 0; r < 16; ++r) msh[rgl][r] = m[r];
  }
  __syncthreads();
  if (half == 0 && lane == 0) {
#pragma unroll
    for (int r = 0; r < 16; ++r) {
      int g = grow0 + r;
      float q = XPf[(size_t)g * 8 + 6];
      float mm = fmaxf(m[r], msh[rgl][r]);
      float f_t = q - 2.0f * mm;
      float fo = prev ? 0.5f * (prev[g] + f_t) : f_t;
      if (outp) outp[g] = fo;
      if (Hs_out) Hs_out[g] = 0.5f * (fo - q - EPS1LNM);
    }
  }
}

// ==== K7: final mean ========================================================
__global__ __launch_bounds__(256) void final_kernel(
    const float* __restrict__ FNG, float* __restrict__ out) {
  float acc = 0.0f;
  for (int i = threadIdx.x; i < PTS_TOTAL; i += 256) acc += FNG[i];
  __shared__ float sh[256];
  sh[threadIdx.x] = acc;
  __syncthreads();
  for (int st = 128; st > 0; st >>= 1) {
    if (threadIdx.x < st) sh[threadIdx.x] += sh[threadIdx.x + st];
    __syncthreads();
  }
  if (threadIdx.x == 0) out[0] = sh[0] * (10.0f / (float)ROWS);
}

extern "C" void kernel_launch(void* const* d_in, const int* in_sizes, int n_in,
                              void* d_out, int out_size, void* d_ws,
                              size_t ws_size, hipStream_t stream) {
  const float* x = (const float*)d_in[0];
  const float* y = (const float*)d_in[1];
  float* out = (float*)d_out;
  float* w = (float*)d_ws;

  float* sc   = w;                    // [0]=eps0, [1]=s
  float* MOM  = w + 64;               // 512 floats: MOM1 (256) + MOM2 (256)
  float* MOM1 = MOM;
  float* MOM2 = MOM + 256;
  float* base = w + 1024;
  float4* XP  = (float4*)base;                    // 32768 pts * 8f = 262144
  uint4* CREC = (uint4*)(base + 262144);          // 32768 * 16B = 131072 f
  float* Hs2  = base + 262144 + 131072;           // 32768
  float* Hs3  = Hs2 + PTS_TOTAL;                  // 32768
  float* FG1  = Hs3 + PTS_TOTAL;                  // 32768
  float* FG2  = FG1 + PTS_TOTAL;                  // 32768
  float* FNG  = FG2 + PTS_TOTAL;                  // 32768

  setup_kernel<<<1, 1024, 0, stream>>>(x, y, sc, MOM);
  pack_kernel<<<PTS_TOTAL / 256, 256, 0, stream>>>(x, y, XP, CREC, sc, MOM1);
  rows1_kernel<<<PTS_TOTAL / 256, 256, 0, stream>>>(XP, MOM1, MOM2, FG1, sc);
  rows2_kernel<<<PTS_TOTAL / 256, 256, 0, stream>>>(XP, MOM2, FG1, FG2, Hs2, sc);
  // pair 3: f3/g3 (0.5-avg with FG2) -> Hs3 only
  softmax_pair_kernel<<<1024, 256, 0, stream>>>(CREC, (const float*)XP, Hs2,
                                                FG2, nullptr, Hs3);
  // pair 4: f_new/g_new -> FNG
  softmax_pair_kernel<<<1024, 256, 0, stream>>>(CREC, (const float*)XP, Hs3,
                                                nullptr, FNG, nullptr);
  final_kernel<<<1, 256, 0, stream>>>(FNG, out);
}

// Round 11
// 130.373 us; speedup vs baseline: 1.4085x; 1.2905x over previous
//
#include <hip/hip_runtime.h>

#define B_ 4
#define N_ 4096
#define ROWS (B_ * N_)            // 16384 per side
#define PTS_TOTAL (2 * ROWS)      // 32768 points

#define LOG2E 1.4426950408889634f
#define LN2   0.6931471805599453f
#define EPS1  1e-4f
#define NEG_LOG2M (-12.0f)              /* -log2(4096) */
#define EPS1LNM 8.317766166719343e-4f   /* eps1 * ln(4096) */
#define ENC_STRIDE 32

typedef _Float16 h2 __attribute__((ext_vector_type(2)));

__device__ inline float fexp2(float x) { return __builtin_amdgcn_exp2f(x); }
__device__ inline float flog2(float x) { return __builtin_amdgcn_logf(x); }

__device__ inline unsigned fenc(float f) {
  unsigned u = __float_as_uint(f);
  return (u & 0x80000000u) ? ~u : (u | 0x80000000u);
}
__device__ inline float fdec(unsigned u) {
  return (u & 0x80000000u) ? __uint_as_float(u & 0x7fffffffu)
                           : __uint_as_float(~u);
}
__device__ inline float fdot2f(h2 a, h2 b, float c) {
#if defined(__has_builtin) && __has_builtin(__builtin_amdgcn_fdot2)
  return __builtin_amdgcn_fdot2(a, b, c, false);
#else
  return (float)a.x * (float)b.x + (float)a.y * (float)b.y + c;
#endif
}
__device__ inline h2 bch2(unsigned u) { return __builtin_bit_cast(h2, u); }
__device__ inline unsigned pkh2(float a, float b) {
  h2 hv; hv.x = (_Float16)a; hv.y = (_Float16)b;
  return __builtin_bit_cast(unsigned, hv);
}

// ==== K0: init enc slots, zero moments and out =============================
__global__ void init_kernel(unsigned* enc, float* MOM, float* out) {
  int t = threadIdx.x;
  if (t < 13) enc[t * ENC_STRIDE] = 0u;
  if (t < 512) MOM[t] = 0.0f;
  if (t == 0) out[0] = 0.0f;
}

// ==== K1: 128-block reduce: 13 flip-encoded maxes -> enc ===================
__global__ __launch_bounds__(256) void reduce_kernel(
    const float* __restrict__ x, const float* __restrict__ y,
    unsigned* __restrict__ enc) {
  int idx = blockIdx.x * 256 + threadIdx.x;   // 0..32767
  bool isx = idx < ROWS;
  const float* p = (isx ? x : y) + (size_t)(isx ? idx : idx - ROWS) * 6;
  float d[6];
#pragma unroll
  for (int k = 0; k < 6; ++k) d[k] = p[k];
  unsigned e[13];
  e[0] = fenc(d[0] * d[0] + d[1] * d[1] + d[2] * d[2]);
#pragma unroll
  for (int k = 0; k < 6; ++k) {
    e[1 + k] = fenc(d[k]);
    e[7 + k] = fenc(-d[k]);
  }
#pragma unroll
  for (int off = 32; off > 0; off >>= 1) {
#pragma unroll
    for (int k = 0; k < 13; ++k) {
      unsigned o = (unsigned)__shfl_xor((int)e[k], off);
      e[k] = e[k] > o ? e[k] : o;
    }
  }
  __shared__ unsigned sh[4][13];
  int wave = threadIdx.x >> 6, lane = threadIdx.x & 63;
  if (lane == 0) {
#pragma unroll
    for (int k = 0; k < 13; ++k) sh[wave][k] = e[k];
  }
  __syncthreads();
  if (threadIdx.x < 13) {
    unsigned v = sh[0][threadIdx.x];
#pragma unroll
    for (int w = 1; w < 4; ++w) v = v > sh[w][threadIdx.x] ? v : sh[w][threadIdx.x];
    atomicMax(&enc[threadIdx.x * ENC_STRIDE], v);
  }
}

// ==== K2: pack XP (f32) + 16B f16 records + eps0 + mom1 partials ===========
__global__ __launch_bounds__(256) void pack_kernel(
    const float* __restrict__ x, const float* __restrict__ y,
    float4* __restrict__ XP, uint4* __restrict__ CREC,
    const unsigned* __restrict__ enc, float* __restrict__ sc,
    float* __restrict__ MOM1) {
  int g = blockIdx.x * 256 + threadIdx.x;   // 0..32767
  int side = g >> 14, local = g & (ROWS - 1), batch = local >> 12;
  float s = 1.0f / (sqrtf(fdec(enc[0])) + 1e-6f);
  float eps0 = 0.0f;
#pragma unroll
  for (int k = 0; k < 6; ++k) {
    float dd = fdec(enc[(1 + k) * ENC_STRIDE]) + fdec(enc[(7 + k) * ENC_STRIDE]);
    eps0 += dd * dd;
  }
  if (g == 0) sc[0] = eps0;

  const float* p = (side ? y : x) + (size_t)local * 6;
  float v[6];
  v[0] = p[0] * s; v[1] = p[1] * s; v[2] = p[2] * s;
  v[3] = 0.1f * fminf(fmaxf(p[3], 0.0f), 1.0f);
  v[4] = 0.1f * fminf(fmaxf(p[4], 0.0f), 1.0f);
  v[5] = 0.1f * fminf(fmaxf(p[5], 0.0f), 1.0f);
  float q = v[0]*v[0] + v[1]*v[1] + v[2]*v[2] + v[3]*v[3] + v[4]*v[4] + v[5]*v[5];
  XP[(size_t)g * 2]     = make_float4(v[0], v[1], v[2], v[3]);
  XP[(size_t)g * 2 + 1] = make_float4(v[4], v[5], q, 0.0f);
  CREC[g] = (uint4){pkh2(v[0], v[1]), pkh2(v[2], v[3]), pkh2(v[4], v[5]), 0u};

  float w = fexp2(NEG_LOG2M - q * (LOG2E / eps0));
  float acc[28];
  acc[0] = w;
  int kk = 1;
#pragma unroll
  for (int d = 0; d < 6; ++d) acc[kk++] = w * v[d];
#pragma unroll
  for (int d = 0; d < 6; ++d) {
    float wv = w * v[d];
#pragma unroll
    for (int e = d; e < 6; ++e) acc[kk++] = wv * v[e];
  }
#pragma unroll
  for (int off = 32; off > 0; off >>= 1) {
#pragma unroll
    for (int k = 0; k < 28; ++k) acc[k] += __shfl_xor(acc[k], off);
  }
  __shared__ float sh[4][28];
  int wave = threadIdx.x >> 6, lane = threadIdx.x & 63;
  if (lane == 0) {
#pragma unroll
    for (int k = 0; k < 28; ++k) sh[wave][k] = acc[k];
  }
  __syncthreads();
  if (threadIdx.x < 28) {
    float vv = (sh[0][threadIdx.x] + sh[1][threadIdx.x]) +
               (sh[2][threadIdx.x] + sh[3][threadIdx.x]);
    atomicAdd(&MOM1[(side * 4 + batch) * 32 + threadIdx.x], vv);
  }
}

// ---- Taylor softmin evaluation helper (eps0 regime) ----
__device__ inline float taylor_f(const float* __restrict__ M, const float* v,
                                 float q, float eps0) {
  float sc2 = 2.0f * LOG2E / eps0;
  float p[6];
#pragma unroll
  for (int d = 0; d < 6; ++d) p[d] = v[d] * sc2;
  float t1 = 0.0f;
#pragma unroll
  for (int d = 0; d < 6; ++d) t1 += p[d] * M[1 + d];
  float t2 = 0.0f;
  int kk = 7;
#pragma unroll
  for (int d = 0; d < 6; ++d) {
#pragma unroll
    for (int e = d; e < 6; ++e) {
      float coef = (d == e) ? 1.0f : 2.0f;
      t2 += coef * p[d] * p[e] * M[kk];
      kk++;
    }
  }
  float S = M[0] + LN2 * t1 + (0.5f * LN2 * LN2) * t2;
  return q - eps0 * LN2 * flog2(S);
}

// ==== K3: rows pair-1 + mom2 partials ======================================
__global__ __launch_bounds__(256) void rows1_kernel(
    const float4* __restrict__ XP, const float* __restrict__ MOM1,
    float* __restrict__ MOM2, float* __restrict__ FG1,
    const float* __restrict__ sc) {
  int g = blockIdx.x * 256 + threadIdx.x;
  int side = g >> 14, local = g & (ROWS - 1), batch = local >> 12;
  float eps0 = sc[0];
  float4 a = XP[(size_t)g * 2], b = XP[(size_t)g * 2 + 1];
  float v[6] = {a.x, a.y, a.z, a.w, b.x, b.y};
  float q = b.z;
  const float* M = MOM1 + (((side ^ 1) * 4 + batch) * 32);
  float f1 = taylor_f(M, v, q, eps0);
  FG1[g] = f1;
  float w = fexp2(NEG_LOG2M + (f1 - q) * (LOG2E / eps0));
  float acc[28];
  acc[0] = w;
  int kk = 1;
#pragma unroll
  for (int d = 0; d < 6; ++d) acc[kk++] = w * v[d];
#pragma unroll
  for (int d = 0; d < 6; ++d) {
    float wv = w * v[d];
#pragma unroll
    for (int e = d; e < 6; ++e) acc[kk++] = wv * v[e];
  }
#pragma unroll
  for (int off = 32; off > 0; off >>= 1) {
#pragma unroll
    for (int k = 0; k < 28; ++k) acc[k] += __shfl_xor(acc[k], off);
  }
  __shared__ float sh[4][28];
  int wave = threadIdx.x >> 6, lane = threadIdx.x & 63;
  if (lane == 0) {
#pragma unroll
    for (int k = 0; k < 28; ++k) sh[wave][k] = acc[k];
  }
  __syncthreads();
  if (threadIdx.x < 28) {
    float vv = (sh[0][threadIdx.x] + sh[1][threadIdx.x]) +
               (sh[2][threadIdx.x] + sh[3][threadIdx.x]);
    atomicAdd(&MOM2[(side * 4 + batch) * 32 + threadIdx.x], vv);
  }
}

// ==== K4: rows pair-2 -> FG2 + rescaled half-units Hs2 =====================
__global__ __launch_bounds__(256) void rows2_kernel(
    const float4* __restrict__ XP, const float* __restrict__ MOM2,
    const float* __restrict__ FG1, float* __restrict__ FG2,
    float* __restrict__ Hs2, const float* __restrict__ sc) {
  int g = blockIdx.x * 256 + threadIdx.x;
  int side = g >> 14, local = g & (ROWS - 1), batch = local >> 12;
  float eps0 = sc[0];
  float4 a = XP[(size_t)g * 2], b = XP[(size_t)g * 2 + 1];
  float v[6] = {a.x, a.y, a.z, a.w, b.x, b.y};
  float q = b.z;
  const float* M = MOM2 + (((side ^ 1) * 4 + batch) * 32);
  float f_t = taylor_f(M, v, q, eps0);
  float f2v = 0.5f * (FG1[g] + f_t);
  FG2[g] = f2v;
  Hs2[g] = 0.5f * (f2v - q - EPS1LNM);
}

// ==== K5/K6: eps1 softmin (pure max), fdot2, 16 rows x 4 column quarters ===
// block = 1 rowgroup of 16 rows; 4 waves each own 1024 cols; LDS merge.
__global__ __launch_bounds__(256) void softmax_pair_kernel(
    const uint4* __restrict__ CREC, const float* __restrict__ XPf,
    const float* __restrict__ Hs_in, const float* __restrict__ prev,
    float* __restrict__ outp, float* __restrict__ Hs_out,
    float* __restrict__ outsum) {
  int t = threadIdx.x;
  int wave = t >> 6, lane = t & 63;
  int grow0 = blockIdx.x * 16;                // global row base (0..32767)
  int side = grow0 >> 14;
  int batch = (grow0 & (ROWS - 1)) >> 12;
  int colrec0 = (side ^ 1) * ROWS + batch * 4096 + wave * 1024;

  h2 P01[16], P23[16], P45[16];
#pragma unroll
  for (int r = 0; r < 16; ++r) {
    uint4 R = CREC[grow0 + r];
    P01[r] = bch2(R.x); P23[r] = bch2(R.y); P45[r] = bch2(R.z);
  }

  float m[16];
#pragma unroll
  for (int r = 0; r < 16; ++r) m[r] = -3.0e38f;

#pragma unroll 2
  for (int it = 0; it < 8; ++it) {
    int j0 = colrec0 + it * 128 + 2 * lane;
    uint4 A = CREC[j0];
    uint4 Bv = CREC[j0 + 1];
    float2 hs = *(const float2*)(Hs_in + j0);
    h2 a01 = bch2(A.x), a23 = bch2(A.y), a45 = bch2(A.z);
    h2 b01 = bch2(Bv.x), b23 = bch2(Bv.y), b45 = bch2(Bv.z);
#pragma unroll
    for (int r = 0; r < 16; ++r) {
      float v1 = fdot2f(a01, P01[r], hs.x);
      v1 = fdot2f(a23, P23[r], v1);
      v1 = fdot2f(a45, P45[r], v1);
      float v2 = fdot2f(b01, P01[r], hs.y);
      v2 = fdot2f(b23, P23[r], v2);
      v2 = fdot2f(b45, P45[r], v2);
      m[r] = fmaxf(m[r], fmaxf(v1, v2));
    }
  }

#pragma unroll
  for (int off = 32; off > 0; off >>= 1) {
#pragma unroll
    for (int r = 0; r < 16; ++r) m[r] = fmaxf(m[r], __shfl_xor(m[r], off));
  }

  __shared__ float msh[4][16];
  if (lane == 0) {
#pragma unroll
    for (int r = 0; r < 16; ++r) msh[wave][r] = m[r];
  }
  __syncthreads();
  if (wave == 0 && lane < 16) {
    int g = grow0 + lane;
    float mm = fmaxf(fmaxf(msh[0][lane], msh[1][lane]),
                     fmaxf(msh[2][lane], msh[3][lane]));
    float q = XPf[(size_t)g * 8 + 6];
    float f_t = q - 2.0f * mm;
    float fo = prev ? 0.5f * (prev[g] + f_t) : f_t;
    if (outp) outp[g] = fo;
    if (Hs_out) Hs_out[g] = 0.5f * (fo - q - EPS1LNM);
    if (outsum) {
      __shared__ float fsh[16];
      fsh[lane] = fo;
      // same wave: lockstep, no barrier needed
      if (lane == 0) {
        float ssum = 0.0f;
#pragma unroll
        for (int r = 0; r < 16; ++r) ssum += fsh[r];
        atomicAdd(outsum, ssum * (10.0f / (float)ROWS));
      }
    }
  }
}

extern "C" void kernel_launch(void* const* d_in, const int* in_sizes, int n_in,
                              void* d_out, int out_size, void* d_ws,
                              size_t ws_size, hipStream_t stream) {
  const float* x = (const float*)d_in[0];
  const float* y = (const float*)d_in[1];
  float* out = (float*)d_out;
  float* w = (float*)d_ws;
  unsigned* enc = (unsigned*)d_ws;    // 13 slots at stride 32 (words 0..415)
  float* sc   = w + 448;              // [0]=eps0
  float* MOM  = w + 512;              // 512 floats
  float* MOM1 = MOM;
  float* MOM2 = MOM + 256;
  float* base = w + 1024;
  float4* XP  = (float4*)base;                    // 262144 floats
  uint4* CREC = (uint4*)(base + 262144);          // 131072 floats-equiv
  float* Hs2  = base + 262144 + 131072;
  float* Hs3  = Hs2 + PTS_TOTAL;
  float* FG1  = Hs3 + PTS_TOTAL;
  float* FG2  = FG1 + PTS_TOTAL;

  init_kernel<<<1, 512, 0, stream>>>(enc, MOM, out);
  reduce_kernel<<<PTS_TOTAL / 256, 256, 0, stream>>>(x, y, enc);
  pack_kernel<<<PTS_TOTAL / 256, 256, 0, stream>>>(x, y, XP, CREC, enc, sc,
                                                   MOM1);
  rows1_kernel<<<PTS_TOTAL / 256, 256, 0, stream>>>(XP, MOM1, MOM2, FG1, sc);
  rows2_kernel<<<PTS_TOTAL / 256, 256, 0, stream>>>(XP, MOM2, FG1, FG2, Hs2, sc);
  // pair 3: Hs3 only (0.5-avg with FG2)
  softmax_pair_kernel<<<2048, 256, 0, stream>>>(CREC, (const float*)XP, Hs2,
                                                FG2, nullptr, Hs3, nullptr);
  // pair 4: final mean folded in via atomicAdd
  softmax_pair_kernel<<<2048, 256, 0, stream>>>(CREC, (const float*)XP, Hs3,
                                                nullptr, nullptr, nullptr, out);
}

// Round 12
// 123.344 us; speedup vs baseline: 1.4888x; 1.0570x over previous
//
#include <hip/hip_runtime.h>

#define B_ 4
#define N_ 4096
#define ROWS (B_ * N_)            // 16384 per side
#define PTS_TOTAL (2 * ROWS)      // 32768 points

#define LOG2E 1.4426950408889634f
#define LN2   0.6931471805599453f
#define EPS1  1e-4f
#define NEG_LOG2M (-12.0f)              /* -log2(4096) */
#define EPS1LNM 8.317766166719343e-4f   /* eps1 * ln(4096) */
#define ENC_STRIDE 32

typedef _Float16 h2 __attribute__((ext_vector_type(2)));

__device__ inline float fexp2(float x) { return __builtin_amdgcn_exp2f(x); }
__device__ inline float flog2(float x) { return __builtin_amdgcn_logf(x); }

__device__ inline unsigned fenc(float f) {
  unsigned u = __float_as_uint(f);
  return (u & 0x80000000u) ? ~u : (u | 0x80000000u);
}
__device__ inline float fdec(unsigned u) {
  return (u & 0x80000000u) ? __uint_as_float(u & 0x7fffffffu)
                           : __uint_as_float(~u);
}
__device__ inline float fdot2f(h2 a, h2 b, float c) {
#if defined(__has_builtin) && __has_builtin(__builtin_amdgcn_fdot2)
  return __builtin_amdgcn_fdot2(a, b, c, false);
#else
  return (float)a.x * (float)b.x + (float)a.y * (float)b.y + c;
#endif
}
__device__ inline h2 bch2(unsigned u) { return __builtin_bit_cast(h2, u); }
__device__ inline unsigned bcu(h2 v) { return __builtin_bit_cast(unsigned, v); }
__device__ inline unsigned pkh2(float a, float b) {
  h2 hv; hv.x = (_Float16)a; hv.y = (_Float16)b;
  return __builtin_bit_cast(unsigned, hv);
}

// ==== K0: init enc slots, zero moments =====================================
__global__ void init_kernel(unsigned* enc, float* MOM) {
  int t = threadIdx.x;
  if (t < 13) enc[t * ENC_STRIDE] = 0u;
  if (t < 512) MOM[t] = 0.0f;
}

// ==== K1: 128-block reduce: 13 flip-encoded maxes ==========================
__global__ __launch_bounds__(256) void reduce_kernel(
    const float* __restrict__ x, const float* __restrict__ y,
    unsigned* __restrict__ enc) {
  int idx = blockIdx.x * 256 + threadIdx.x;   // 0..32767
  bool isx = idx < ROWS;
  const float* p = (isx ? x : y) + (size_t)(isx ? idx : idx - ROWS) * 6;
  float d[6];
#pragma unroll
  for (int k = 0; k < 6; ++k) d[k] = p[k];
  unsigned e[13];
  e[0] = fenc(d[0] * d[0] + d[1] * d[1] + d[2] * d[2]);
#pragma unroll
  for (int k = 0; k < 6; ++k) {
    e[1 + k] = fenc(d[k]);
    e[7 + k] = fenc(-d[k]);
  }
#pragma unroll
  for (int off = 32; off > 0; off >>= 1) {
#pragma unroll
    for (int k = 0; k < 13; ++k) {
      unsigned o = (unsigned)__shfl_xor((int)e[k], off);
      e[k] = e[k] > o ? e[k] : o;
    }
  }
  __shared__ unsigned sh[4][13];
  int wave = threadIdx.x >> 6, lane = threadIdx.x & 63;
  if (lane == 0) {
#pragma unroll
    for (int k = 0; k < 13; ++k) sh[wave][k] = e[k];
  }
  __syncthreads();
  if (threadIdx.x < 13) {
    unsigned v = sh[0][threadIdx.x];
#pragma unroll
    for (int w = 1; w < 4; ++w) v = v > sh[w][threadIdx.x] ? v : sh[w][threadIdx.x];
    atomicMax(&enc[threadIdx.x * ENC_STRIDE], v);
  }
}

// ==== K2: pack XP (f32) + f16 records + eps0 + mom1 partials ===============
__global__ __launch_bounds__(256) void pack_kernel(
    const float* __restrict__ x, const float* __restrict__ y,
    float4* __restrict__ XP, uint4* __restrict__ CRECA,
    const unsigned* __restrict__ enc, float* __restrict__ sc,
    float* __restrict__ MOM1) {
  int g = blockIdx.x * 256 + threadIdx.x;   // 0..32767
  int side = g >> 14, local = g & (ROWS - 1), batch = local >> 12;
  float s = 1.0f / (sqrtf(fdec(enc[0])) + 1e-6f);
  float eps0 = 0.0f;
#pragma unroll
  for (int k = 0; k < 6; ++k) {
    float dd = fdec(enc[(1 + k) * ENC_STRIDE]) + fdec(enc[(7 + k) * ENC_STRIDE]);
    eps0 += dd * dd;
  }
  if (g == 0) sc[0] = eps0;

  const float* p = (side ? y : x) + (size_t)local * 6;
  float v[6];
  v[0] = p[0] * s; v[1] = p[1] * s; v[2] = p[2] * s;
  v[3] = 0.1f * fminf(fmaxf(p[3], 0.0f), 1.0f);
  v[4] = 0.1f * fminf(fmaxf(p[4], 0.0f), 1.0f);
  v[5] = 0.1f * fminf(fmaxf(p[5], 0.0f), 1.0f);
  float q = v[0]*v[0] + v[1]*v[1] + v[2]*v[2] + v[3]*v[3] + v[4]*v[4] + v[5]*v[5];
  XP[(size_t)g * 2]     = make_float4(v[0], v[1], v[2], v[3]);
  XP[(size_t)g * 2 + 1] = make_float4(v[4], v[5], q, 0.0f);
  CRECA[g] = (uint4){pkh2(v[0], v[1]), pkh2(v[2], v[3]), pkh2(v[4], v[5]), 0u};

  float w = fexp2(NEG_LOG2M - q * (LOG2E / eps0));
  float acc[28];
  acc[0] = w;
  int kk = 1;
#pragma unroll
  for (int d = 0; d < 6; ++d) acc[kk++] = w * v[d];
#pragma unroll
  for (int d = 0; d < 6; ++d) {
    float wv = w * v[d];
#pragma unroll
    for (int e = d; e < 6; ++e) acc[kk++] = wv * v[e];
  }
#pragma unroll
  for (int off = 32; off > 0; off >>= 1) {
#pragma unroll
    for (int k = 0; k < 28; ++k) acc[k] += __shfl_xor(acc[k], off);
  }
  __shared__ float sh[4][28];
  int wave = threadIdx.x >> 6, lane = threadIdx.x & 63;
  if (lane == 0) {
#pragma unroll
    for (int k = 0; k < 28; ++k) sh[wave][k] = acc[k];
  }
  __syncthreads();
  if (threadIdx.x < 28) {
    float vv = (sh[0][threadIdx.x] + sh[1][threadIdx.x]) +
               (sh[2][threadIdx.x] + sh[3][threadIdx.x]);
    atomicAdd(&MOM1[(side * 4 + batch) * 32 + threadIdx.x], vv);
  }
}

// ---- Taylor softmin evaluation (eps0 regime) ----
__device__ inline float taylor_f(const float* __restrict__ M, const float* v,
                                 float q, float eps0) {
  float sc2 = 2.0f * LOG2E / eps0;
  float p[6];
#pragma unroll
  for (int d = 0; d < 6; ++d) p[d] = v[d] * sc2;
  float t1 = 0.0f;
#pragma unroll
  for (int d = 0; d < 6; ++d) t1 += p[d] * M[1 + d];
  float t2 = 0.0f;
  int kk = 7;
#pragma unroll
  for (int d = 0; d < 6; ++d) {
#pragma unroll
    for (int e = d; e < 6; ++e) {
      float coef = (d == e) ? 1.0f : 2.0f;
      t2 += coef * p[d] * p[e] * M[kk];
      kk++;
    }
  }
  float S = M[0] + LN2 * t1 + (0.5f * LN2 * LN2) * t2;
  return q - eps0 * LN2 * flog2(S);
}

// ==== K3: rows pair-1 + mom2 partials ======================================
__global__ __launch_bounds__(256) void rows1_kernel(
    const float4* __restrict__ XP, const float* __restrict__ MOM1,
    float* __restrict__ MOM2, float* __restrict__ FG1,
    const float* __restrict__ sc) {
  int g = blockIdx.x * 256 + threadIdx.x;
  int side = g >> 14, local = g & (ROWS - 1), batch = local >> 12;
  float eps0 = sc[0];
  float4 a = XP[(size_t)g * 2], b = XP[(size_t)g * 2 + 1];
  float v[6] = {a.x, a.y, a.z, a.w, b.x, b.y};
  float q = b.z;
  const float* M = MOM1 + (((side ^ 1) * 4 + batch) * 32);
  float f1 = taylor_f(M, v, q, eps0);
  FG1[g] = f1;
  float w = fexp2(NEG_LOG2M + (f1 - q) * (LOG2E / eps0));
  float acc[28];
  acc[0] = w;
  int kk = 1;
#pragma unroll
  for (int d = 0; d < 6; ++d) acc[kk++] = w * v[d];
#pragma unroll
  for (int d = 0; d < 6; ++d) {
    float wv = w * v[d];
#pragma unroll
    for (int e = d; e < 6; ++e) acc[kk++] = wv * v[e];
  }
#pragma unroll
  for (int off = 32; off > 0; off >>= 1) {
#pragma unroll
    for (int k = 0; k < 28; ++k) acc[k] += __shfl_xor(acc[k], off);
  }
  __shared__ float sh[4][28];
  int wave = threadIdx.x >> 6, lane = threadIdx.x & 63;
  if (lane == 0) {
#pragma unroll
    for (int k = 0; k < 28; ++k) sh[wave][k] = acc[k];
  }
  __syncthreads();
  if (threadIdx.x < 28) {
    float vv = (sh[0][threadIdx.x] + sh[1][threadIdx.x]) +
               (sh[2][threadIdx.x] + sh[3][threadIdx.x]);
    atomicAdd(&MOM2[(side * 4 + batch) * 32 + threadIdx.x], vv);
  }
}

// ==== K4: rows pair-2 -> FG2; hs2 (f16) into CRECA[g].w ====================
__global__ __launch_bounds__(256) void rows2_kernel(
    const float4* __restrict__ XP, const float* __restrict__ MOM2,
    const float* __restrict__ FG1, float* __restrict__ FG2,
    unsigned* __restrict__ CRECAu, const float* __restrict__ sc) {
  int g = blockIdx.x * 256 + threadIdx.x;
  int side = g >> 14, local = g & (ROWS - 1), batch = local >> 12;
  float eps0 = sc[0];
  float4 a = XP[(size_t)g * 2], b = XP[(size_t)g * 2 + 1];
  float v[6] = {a.x, a.y, a.z, a.w, b.x, b.y};
  float q = b.z;
  const float* M = MOM2 + (((side ^ 1) * 4 + batch) * 32);
  float f_t = taylor_f(M, v, q, eps0);
  float f2v = 0.5f * (FG1[g] + f_t);
  FG2[g] = f2v;
  float hs2 = 0.5f * (f2v - q - EPS1LNM);
  CRECAu[4 * g + 3] = pkh2(hs2, 0.0f);
}

// ==== K5/K6: eps1 softmin (pure max), fdot2, 8 rows/block, 4 col-quarters ==
// 4096 blocks; hs embedded in record .w; pair-3 writes next-round records.
__global__ __launch_bounds__(256) void softmax_pair_kernel(
    const uint4* __restrict__ CIN, uint4* __restrict__ COUT,
    const float* __restrict__ XPf, const float* __restrict__ prev,
    float* __restrict__ part) {
  int t = threadIdx.x;
  int wave = t >> 6, lane = t & 63;
  int grow0 = blockIdx.x * 8;                 // global row base (0..32767)
  int side = grow0 >> 14;
  int batch = (grow0 & (ROWS - 1)) >> 12;
  int colrec0 = (side ^ 1) * ROWS + batch * 4096 + wave * 1024;

  h2 P01[8], P23[8], P45[8];
#pragma unroll
  for (int r = 0; r < 8; ++r) {
    uint4 R = CIN[grow0 + r];
    P01[r] = bch2(R.x); P23[r] = bch2(R.y); P45[r] = bch2(R.z);
  }

  float m[8];
#pragma unroll
  for (int r = 0; r < 8; ++r) m[r] = -3.0e38f;

#pragma unroll 2
  for (int it = 0; it < 8; ++it) {
    int j0 = colrec0 + it * 128 + 2 * lane;
    uint4 A = CIN[j0];
    uint4 Bv = CIN[j0 + 1];
    float hsA = (float)bch2(A.w).x;
    float hsB = (float)bch2(Bv.w).x;
    h2 a01 = bch2(A.x), a23 = bch2(A.y), a45 = bch2(A.z);
    h2 b01 = bch2(Bv.x), b23 = bch2(Bv.y), b45 = bch2(Bv.z);
#pragma unroll
    for (int r = 0; r < 8; ++r) {
      float v1 = fdot2f(a01, P01[r], hsA);
      v1 = fdot2f(a23, P23[r], v1);
      v1 = fdot2f(a45, P45[r], v1);
      float v2 = fdot2f(b01, P01[r], hsB);
      v2 = fdot2f(b23, P23[r], v2);
      v2 = fdot2f(b45, P45[r], v2);
      m[r] = fmaxf(m[r], fmaxf(v1, v2));
    }
  }

#pragma unroll
  for (int off = 32; off > 0; off >>= 1) {
#pragma unroll
    for (int r = 0; r < 8; ++r) m[r] = fmaxf(m[r], __shfl_xor(m[r], off));
  }

  __shared__ float msh[4][8];
  if (lane == 0) {
#pragma unroll
    for (int r = 0; r < 8; ++r) msh[wave][r] = m[r];
  }
  __syncthreads();
  if (wave == 0 && lane < 8) {
    int r = lane;
    int g = grow0 + r;
    float mm = fmaxf(fmaxf(msh[0][r], msh[1][r]),
                     fmaxf(msh[2][r], msh[3][r]));
    float q = XPf[(size_t)g * 8 + 6];
    float f_t = q - 2.0f * mm;
    float fo = prev ? 0.5f * (prev[g] + f_t) : f_t;
    if (COUT) {
      float hs = 0.5f * (fo - q - EPS1LNM);
      COUT[g] = (uint4){bcu(P01[r]), bcu(P23[r]), bcu(P45[r]), pkh2(hs, 0.0f)};
    }
    if (part) {
      __shared__ float fsh[8];
      fsh[r] = fo;
      if (r == 0) {
        float ssum = 0.0f;
#pragma unroll
        for (int k = 0; k < 8; ++k) ssum += fsh[k];
        part[blockIdx.x] = ssum;
      }
    }
  }
}

// ==== K7: final sum of 4096 per-block partials =============================
__global__ __launch_bounds__(256) void final_kernel(
    const float* __restrict__ part, float* __restrict__ out) {
  float acc = 0.0f;
  for (int i = threadIdx.x; i < 4096; i += 256) acc += part[i];
  __shared__ float sh[256];
  sh[threadIdx.x] = acc;
  __syncthreads();
  for (int st = 128; st > 0; st >>= 1) {
    if (threadIdx.x < st) sh[threadIdx.x] += sh[threadIdx.x + st];
    __syncthreads();
  }
  if (threadIdx.x == 0) out[0] = sh[0] * (10.0f / (float)ROWS);
}

extern "C" void kernel_launch(void* const* d_in, const int* in_sizes, int n_in,
                              void* d_out, int out_size, void* d_ws,
                              size_t ws_size, hipStream_t stream) {
  const float* x = (const float*)d_in[0];
  const float* y = (const float*)d_in[1];
  float* out = (float*)d_out;
  float* w = (float*)d_ws;
  unsigned* enc = (unsigned*)d_ws;    // 13 slots at stride 32 (words 0..415)
  float* sc   = w + 448;              // [0]=eps0
  float* MOM  = w + 512;              // 512 floats
  float* MOM1 = MOM;
  float* MOM2 = MOM + 256;
  float* base = w + 1024;
  float4* XP   = (float4*)base;                   // 262144 floats
  uint4* CRECA = (uint4*)(base + 262144);         // 131072 floats-equiv
  uint4* CRECB = (uint4*)(base + 262144 + 131072);// 131072
  float* FG1   = base + 262144 + 262144;
  float* FG2   = FG1 + PTS_TOTAL;
  float* PART  = FG2 + PTS_TOTAL;                 // 4096

  init_kernel<<<1, 512, 0, stream>>>(enc, MOM);
  reduce_kernel<<<PTS_TOTAL / 256, 256, 0, stream>>>(x, y, enc);
  pack_kernel<<<PTS_TOTAL / 256, 256, 0, stream>>>(x, y, XP, CRECA, enc, sc,
                                                   MOM1);
  rows1_kernel<<<PTS_TOTAL / 256, 256, 0, stream>>>(XP, MOM1, MOM2, FG1, sc);
  rows2_kernel<<<PTS_TOTAL / 256, 256, 0, stream>>>(XP, MOM2, FG1, FG2,
                                                    (unsigned*)CRECA, sc);
  // pair 3: reads CRECA (hs2 in .w), 0.5-avg with FG2, writes CRECB (hs3)
  softmax_pair_kernel<<<4096, 256, 0, stream>>>(CRECA, CRECB, (const float*)XP,
                                                FG2, nullptr);
  // pair 4: reads CRECB, writes per-block partial sums
  softmax_pair_kernel<<<4096, 256, 0, stream>>>(CRECB, nullptr,
                                                (const float*)XP, nullptr, PART);
  final_kernel<<<1, 256, 0, stream>>>(PART, out);
}

// Round 13
// 117.963 us; speedup vs baseline: 1.5567x; 1.0456x over previous
//
#include <hip/hip_runtime.h>

#define B_ 4
#define N_ 4096
#define ROWS (B_ * N_)            // 16384 per side
#define PTS_TOTAL (2 * ROWS)      // 32768 points

#define LOG2E 1.4426950408889634f
#define LN2   0.6931471805599453f
#define EPS1  1e-4f
#define NEG_LOG2M (-12.0f)              /* -log2(4096) */
#define EPS1LNM 8.317766166719343e-4f   /* eps1 * ln(4096) */
#define ENC_STRIDE 32

typedef _Float16 h2 __attribute__((ext_vector_type(2)));
typedef _Float16 v8h __attribute__((ext_vector_type(8)));
typedef float f32x4 __attribute__((ext_vector_type(4)));

__device__ inline float fexp2(float x) { return __builtin_amdgcn_exp2f(x); }
__device__ inline float flog2(float x) { return __builtin_amdgcn_logf(x); }

__device__ inline unsigned fenc(float f) {
  unsigned u = __float_as_uint(f);
  return (u & 0x80000000u) ? ~u : (u | 0x80000000u);
}
__device__ inline float fdec(unsigned u) {
  return (u & 0x80000000u) ? __uint_as_float(u & 0x7fffffffu)
                           : __uint_as_float(~u);
}
__device__ inline unsigned pkh2(float a, float b) {
  h2 hv; hv.x = (_Float16)a; hv.y = (_Float16)b;
  return __builtin_bit_cast(unsigned, hv);
}
__device__ inline v8h bcv8(uint4 u) { return __builtin_bit_cast(v8h, u); }

// ==== K0: init enc slots, zero moments =====================================
__global__ void init_kernel(unsigned* enc, float* MOM) {
  int t = threadIdx.x;
  if (t < 13) enc[t * ENC_STRIDE] = 0u;
  if (t < 512) MOM[t] = 0.0f;
}

// ==== K1: 128-block reduce: 13 flip-encoded maxes ==========================
__global__ __launch_bounds__(256) void reduce_kernel(
    const float* __restrict__ x, const float* __restrict__ y,
    unsigned* __restrict__ enc) {
  int idx = blockIdx.x * 256 + threadIdx.x;   // 0..32767
  bool isx = idx < ROWS;
  const float* p = (isx ? x : y) + (size_t)(isx ? idx : idx - ROWS) * 6;
  float d[6];
#pragma unroll
  for (int k = 0; k < 6; ++k) d[k] = p[k];
  unsigned e[13];
  e[0] = fenc(d[0] * d[0] + d[1] * d[1] + d[2] * d[2]);
#pragma unroll
  for (int k = 0; k < 6; ++k) {
    e[1 + k] = fenc(d[k]);
    e[7 + k] = fenc(-d[k]);
  }
#pragma unroll
  for (int off = 32; off > 0; off >>= 1) {
#pragma unroll
    for (int k = 0; k < 13; ++k) {
      unsigned o = (unsigned)__shfl_xor((int)e[k], off);
      e[k] = e[k] > o ? e[k] : o;
    }
  }
  __shared__ unsigned sh[4][13];
  int wave = threadIdx.x >> 6, lane = threadIdx.x & 63;
  if (lane == 0) {
#pragma unroll
    for (int k = 0; k < 13; ++k) sh[wave][k] = e[k];
  }
  __syncthreads();
  if (threadIdx.x < 13) {
    unsigned v = sh[0][threadIdx.x];
#pragma unroll
    for (int w = 1; w < 4; ++w) v = v > sh[w][threadIdx.x] ? v : sh[w][threadIdx.x];
    atomicMax(&enc[threadIdx.x * ENC_STRIDE], v);
  }
}

// ==== K2: pack XP + AREC (X=1) + BREC (X=hs later) + eps0 + mom1 ===========
__global__ __launch_bounds__(256) void pack_kernel(
    const float* __restrict__ x, const float* __restrict__ y,
    float4* __restrict__ XP, uint4* __restrict__ AREC,
    uint4* __restrict__ BREC, const unsigned* __restrict__ enc,
    float* __restrict__ sc, float* __restrict__ MOM1) {
  int g = blockIdx.x * 256 + threadIdx.x;   // 0..32767
  int side = g >> 14, local = g & (ROWS - 1), batch = local >> 12;
  float s = 1.0f / (sqrtf(fdec(enc[0])) + 1e-6f);
  float eps0 = 0.0f;
#pragma unroll
  for (int k = 0; k < 6; ++k) {
    float dd = fdec(enc[(1 + k) * ENC_STRIDE]) + fdec(enc[(7 + k) * ENC_STRIDE]);
    eps0 += dd * dd;
  }
  if (g == 0) sc[0] = eps0;

  const float* p = (side ? y : x) + (size_t)local * 6;
  float v[6];
  v[0] = p[0] * s; v[1] = p[1] * s; v[2] = p[2] * s;
  v[3] = 0.1f * fminf(fmaxf(p[3], 0.0f), 1.0f);
  v[4] = 0.1f * fminf(fmaxf(p[4], 0.0f), 1.0f);
  v[5] = 0.1f * fminf(fmaxf(p[5], 0.0f), 1.0f);
  float q = v[0]*v[0] + v[1]*v[1] + v[2]*v[2] + v[3]*v[3] + v[4]*v[4] + v[5]*v[5];
  XP[(size_t)g * 2]     = make_float4(v[0], v[1], v[2], v[3]);
  XP[(size_t)g * 2 + 1] = make_float4(v[4], v[5], q, 0.0f);
  unsigned w01 = pkh2(v[0], v[1]), w23 = pkh2(v[2], v[3]), w45 = pkh2(v[4], v[5]);
  AREC[g] = (uint4){w01, w23, w45, pkh2(1.0f, 0.0f)};
  BREC[g] = (uint4){w01, w23, w45, 0u};

  float w = fexp2(NEG_LOG2M - q * (LOG2E / eps0));
  float acc[28];
  acc[0] = w;
  int kk = 1;
#pragma unroll
  for (int d = 0; d < 6; ++d) acc[kk++] = w * v[d];
#pragma unroll
  for (int d = 0; d < 6; ++d) {
    float wv = w * v[d];
#pragma unroll
    for (int e = d; e < 6; ++e) acc[kk++] = wv * v[e];
  }
#pragma unroll
  for (int off = 32; off > 0; off >>= 1) {
#pragma unroll
    for (int k = 0; k < 28; ++k) acc[k] += __shfl_xor(acc[k], off);
  }
  __shared__ float sh[4][28];
  int wave = threadIdx.x >> 6, lane = threadIdx.x & 63;
  if (lane == 0) {
#pragma unroll
    for (int k = 0; k < 28; ++k) sh[wave][k] = acc[k];
  }
  __syncthreads();
  if (threadIdx.x < 28) {
    float vv = (sh[0][threadIdx.x] + sh[1][threadIdx.x]) +
               (sh[2][threadIdx.x] + sh[3][threadIdx.x]);
    atomicAdd(&MOM1[(side * 4 + batch) * 32 + threadIdx.x], vv);
  }
}

// ---- Taylor softmin evaluation (eps0 regime) ----
__device__ inline float taylor_f(const float* __restrict__ M, const float* v,
                                 float q, float eps0) {
  float sc2 = 2.0f * LOG2E / eps0;
  float p[6];
#pragma unroll
  for (int d = 0; d < 6; ++d) p[d] = v[d] * sc2;
  float t1 = 0.0f;
#pragma unroll
  for (int d = 0; d < 6; ++d) t1 += p[d] * M[1 + d];
  float t2 = 0.0f;
  int kk = 7;
#pragma unroll
  for (int d = 0; d < 6; ++d) {
#pragma unroll
    for (int e = d; e < 6; ++e) {
      float coef = (d == e) ? 1.0f : 2.0f;
      t2 += coef * p[d] * p[e] * M[kk];
      kk++;
    }
  }
  float S = M[0] + LN2 * t1 + (0.5f * LN2 * LN2) * t2;
  return q - eps0 * LN2 * flog2(S);
}

// ==== K3: rows pair-1 + mom2 partials ======================================
__global__ __launch_bounds__(256) void rows1_kernel(
    const float4* __restrict__ XP, const float* __restrict__ MOM1,
    float* __restrict__ MOM2, float* __restrict__ FG1,
    const float* __restrict__ sc) {
  int g = blockIdx.x * 256 + threadIdx.x;
  int side = g >> 14, local = g & (ROWS - 1), batch = local >> 12;
  float eps0 = sc[0];
  float4 a = XP[(size_t)g * 2], b = XP[(size_t)g * 2 + 1];
  float v[6] = {a.x, a.y, a.z, a.w, b.x, b.y};
  float q = b.z;
  const float* M = MOM1 + (((side ^ 1) * 4 + batch) * 32);
  float f1 = taylor_f(M, v, q, eps0);
  FG1[g] = f1;
  float w = fexp2(NEG_LOG2M + (f1 - q) * (LOG2E / eps0));
  float acc[28];
  acc[0] = w;
  int kk = 1;
#pragma unroll
  for (int d = 0; d < 6; ++d) acc[kk++] = w * v[d];
#pragma unroll
  for (int d = 0; d < 6; ++d) {
    float wv = w * v[d];
#pragma unroll
    for (int e = d; e < 6; ++e) acc[kk++] = wv * v[e];
  }
#pragma unroll
  for (int off = 32; off > 0; off >>= 1) {
#pragma unroll
    for (int k = 0; k < 28; ++k) acc[k] += __shfl_xor(acc[k], off);
  }
  __shared__ float sh[4][28];
  int wave = threadIdx.x >> 6, lane = threadIdx.x & 63;
  if (lane == 0) {
#pragma unroll
    for (int k = 0; k < 28; ++k) sh[wave][k] = acc[k];
  }
  __syncthreads();
  if (threadIdx.x < 28) {
    float vv = (sh[0][threadIdx.x] + sh[1][threadIdx.x]) +
               (sh[2][threadIdx.x] + sh[3][threadIdx.x]);
    atomicAdd(&MOM2[(side * 4 + batch) * 32 + threadIdx.x], vv);
  }
}

// ==== K4: rows pair-2 -> FG2; hs2 (f16) into BREC[g].w =====================
__global__ __launch_bounds__(256) void rows2_kernel(
    const float4* __restrict__ XP, const float* __restrict__ MOM2,
    const float* __restrict__ FG1, float* __restrict__ FG2,
    unsigned* __restrict__ BRECu, const float* __restrict__ sc) {
  int g = blockIdx.x * 256 + threadIdx.x;
  int side = g >> 14, local = g & (ROWS - 1), batch = local >> 12;
  float eps0 = sc[0];
  float4 a = XP[(size_t)g * 2], b = XP[(size_t)g * 2 + 1];
  float v[6] = {a.x, a.y, a.z, a.w, b.x, b.y};
  float q = b.z;
  const float* M = MOM2 + (((side ^ 1) * 4 + batch) * 32);
  float f_t = taylor_f(M, v, q, eps0);
  float f2v = 0.5f * (FG1[g] + f_t);
  FG2[g] = f2v;
  float hs2 = 0.5f * (f2v - q - EPS1LNM);
  BRECu[4 * g + 3] = pkh2(hs2, 0.0f);
}

// ==== K5/K6: eps1 softmin via MFMA ========================================
// D[i][j] = u_i.u_j + hs_j  (A rec X=1, B rec X=hs, K=32 with k>=8 zero).
// Block = 32 rows x 4 col-quarter waves; wave = 2 A-tiles x 64 B-tiles.
__global__ __launch_bounds__(256) void softmax_pair_kernel(
    const uint4* __restrict__ AREC, const uint4* __restrict__ BIN,
    uint4* __restrict__ BOUT, const float* __restrict__ XPf,
    const float* __restrict__ prev, float* __restrict__ part) {
  int t = threadIdx.x;
  int wave = t >> 6, lane = t & 63;
  int l16 = lane & 15;
  bool ld = lane < 16;                        // quad 0 carries k=0..7
  int grow0 = blockIdx.x * 32;                // 32 rows per block
  int side = grow0 >> 14;
  int batch = (grow0 & (ROWS - 1)) >> 12;
  int colrec0 = (side ^ 1) * ROWS + batch * 4096 + wave * 1024;

  uint4 z4 = (uint4){0u, 0u, 0u, 0u};
  uint4 a1u = z4, a2u = z4;
  if (ld) {
    a1u = AREC[grow0 + l16];
    a2u = AREC[grow0 + 16 + l16];
  }
  v8h a1 = bcv8(a1u), a2 = bcv8(a2u);

  f32x4 m2a = {-3.0e38f, -3.0e38f, -3.0e38f, -3.0e38f};
  f32x4 m2b = m2a;
  const f32x4 cz = {0.0f, 0.0f, 0.0f, 0.0f};

#pragma unroll 4
  for (int tt = 0; tt < 64; ++tt) {
    uint4 bu = z4;
    if (ld) bu = BIN[colrec0 + tt * 16 + l16];
    v8h b = bcv8(bu);
    f32x4 d1 = __builtin_amdgcn_mfma_f32_16x16x32_f16(a1, b, cz, 0, 0, 0);
    f32x4 d2 = __builtin_amdgcn_mfma_f32_16x16x32_f16(a2, b, cz, 0, 0, 0);
    m2a = __builtin_elementwise_max(m2a, d1);
    m2b = __builtin_elementwise_max(m2b, d2);
  }

  // reduce over the 16 col-lanes (C/D: col=lane&15, row=quad*4+reg)
#pragma unroll
  for (int off = 1; off <= 8; off <<= 1) {
#pragma unroll
    for (int r = 0; r < 4; ++r) {
      m2a[r] = fmaxf(m2a[r], __shfl_xor(m2a[r], off));
      m2b[r] = fmaxf(m2b[r], __shfl_xor(m2b[r], off));
    }
  }

  __shared__ float lm[4][32];
  __shared__ float fsh[32];
  if (l16 == 0) {
    int qd = lane >> 4;
#pragma unroll
    for (int r = 0; r < 4; ++r) {
      lm[wave][qd * 4 + r] = m2a[r];
      lm[wave][16 + qd * 4 + r] = m2b[r];
    }
  }
  __syncthreads();
  if (t < 32) {
    int g = grow0 + t;
    float m = fmaxf(fmaxf(lm[0][t], lm[1][t]), fmaxf(lm[2][t], lm[3][t]));
    float q = XPf[(size_t)g * 8 + 6];
    float f_t = q - 2.0f * m;
    float fo = prev ? 0.5f * (prev[g] + f_t) : f_t;
    if (BOUT) {
      float hs = 0.5f * (fo - q - EPS1LNM);
      uint4 ar = AREC[g];
      BOUT[g] = (uint4){ar.x, ar.y, ar.z, pkh2(hs, 0.0f)};
    }
    if (part) {
      fsh[t] = fo;
      __builtin_amdgcn_s_waitcnt(0);  // lgkm drain within wave
      if (t == 0) {
        float ssum = 0.0f;
#pragma unroll
        for (int k = 0; k < 32; ++k) ssum += fsh[k];
        part[blockIdx.x] = ssum;
      }
    }
  }
}

// ==== K7: final sum of 1024 per-block partials =============================
__global__ __launch_bounds__(256) void final_kernel(
    const float* __restrict__ part, float* __restrict__ out) {
  float acc = 0.0f;
  for (int i = threadIdx.x; i < 1024; i += 256) acc += part[i];
  __shared__ float sh[256];
  sh[threadIdx.x] = acc;
  __syncthreads();
  for (int st = 128; st > 0; st >>= 1) {
    if (threadIdx.x < st) sh[threadIdx.x] += sh[threadIdx.x + st];
    __syncthreads();
  }
  if (threadIdx.x == 0) out[0] = sh[0] * (10.0f / (float)ROWS);
}

extern "C" void kernel_launch(void* const* d_in, const int* in_sizes, int n_in,
                              void* d_out, int out_size, void* d_ws,
                              size_t ws_size, hipStream_t stream) {
  const float* x = (const float*)d_in[0];
  const float* y = (const float*)d_in[1];
  float* out = (float*)d_out;
  float* w = (float*)d_ws;
  unsigned* enc = (unsigned*)d_ws;    // 13 slots at stride 32 (words 0..415)
  float* sc   = w + 448;              // [0]=eps0
  float* MOM  = w + 512;              // 512 floats
  float* MOM1 = MOM;
  float* MOM2 = MOM + 256;
  float* base = w + 1024;
  float4* XP   = (float4*)base;                   // 262144 floats
  uint4* AREC  = (uint4*)(base + 262144);         // 131072 floats-equiv
  uint4* BRECA = (uint4*)(base + 262144 + 131072);
  uint4* BRECB = (uint4*)(base + 262144 + 262144);
  float* FG1   = base + 262144 + 262144 + 131072;
  float* FG2   = FG1 + PTS_TOTAL;
  float* PART  = FG2 + PTS_TOTAL;                 // 1024

  init_kernel<<<1, 512, 0, stream>>>(enc, MOM);
  reduce_kernel<<<PTS_TOTAL / 256, 256, 0, stream>>>(x, y, enc);
  pack_kernel<<<PTS_TOTAL / 256, 256, 0, stream>>>(x, y, XP, AREC, BRECA, enc,
                                                   sc, MOM1);
  rows1_kernel<<<PTS_TOTAL / 256, 256, 0, stream>>>(XP, MOM1, MOM2, FG1, sc);
  rows2_kernel<<<PTS_TOTAL / 256, 256, 0, stream>>>(XP, MOM2, FG1, FG2,
                                                    (unsigned*)BRECA, sc);
  // pair 3: reads BRECA (hs2), 0.5-avg with FG2, writes BRECB (hs3)
  softmax_pair_kernel<<<1024, 256, 0, stream>>>(AREC, BRECA, BRECB,
                                                (const float*)XP, FG2, nullptr);
  // pair 4: reads BRECB, per-block partials
  softmax_pair_kernel<<<1024, 256, 0, stream>>>(AREC, BRECB, nullptr,
                                                (const float*)XP, nullptr, PART);
  final_kernel<<<1, 256, 0, stream>>>(PART, out);
}